// Round 1
// baseline (11385.921 us; speedup 1.0000x reference)
//
#include <hip/hip_runtime.h>
#include <math.h>

#define NNODES 20000
#define NEDGES 320000

// ---------------- embed: NeRF positional encoding ----------------
__global__ __launch_bounds__(256) void embed_kernel(const float* __restrict__ x,
                                                    float* __restrict__ h) {
  int n = blockIdx.x * blockDim.x + threadIdx.x;
  if (n >= NNODES) return;
  const float* xr = x + (size_t)n * 20;
  float* hr = h + (size_t)n * 200;
#pragma unroll
  for (int g = 0; g < 3; ++g) {
    float v0 = xr[g * 3 + 0], v1 = xr[g * 3 + 1], v2 = xr[g * 3 + 2];
    float* o = hr + g * 63;
    o[0] = v0; o[1] = v1; o[2] = v2;
    float f = 1.0f;
    for (int fr = 0; fr < 10; ++fr) {
      float s0, c0, s1, c1, s2, c2;
      sincosf(v0 * f, &s0, &c0);
      sincosf(v1 * f, &s1, &c1);
      sincosf(v2 * f, &s2, &c2);
      int base = 3 + fr * 6;
      o[base + 0] = s0; o[base + 1] = s1; o[base + 2] = s2;
      o[base + 3] = c0; o[base + 4] = c1; o[base + 5] = c2;
      f *= 2.0f;
    }
  }
  for (int j = 0; j < 11; ++j) hr[189 + j] = xr[9 + j];
}

// ---------------- per-node in-degree counts (layer-invariant) ----------------
__global__ __launch_bounds__(256) void count_kernel(const int* __restrict__ edst,
                                                    int* __restrict__ cnt) {
  int e = blockIdx.x * blockDim.x + threadIdx.x;
  if (e < NEDGES) atomicAdd(&cnt[edst[e]], 1);
}

// ---------------- node GEMM: AV[n, 0:dout]=h@W1a+b1, AV[n, dout:2dout]=h@W1b ----
// C = H(M x din) @ Wcat(din x 2*dout); Wcat[k][c] = c<dout ? W1[k][c] : W1[din+k][c-dout]
__global__ __launch_bounds__(256) void node_gemm_kernel(
    const float* __restrict__ H, int ldh, int din, int dout,
    const float* __restrict__ W1, const float* __restrict__ b1,
    float* __restrict__ AV) {
  __shared__ float sA[16][65];
  __shared__ float sW[16][64];
  const int NN2 = 2 * dout;
  int tid = threadIdx.x;
  int bR = blockIdx.y * 64, bC = blockIdx.x * 64;
  int ty = tid / 16, tx = tid % 16;
  float acc[4][4] = {{0.f}};
  for (int k0 = 0; k0 < din; k0 += 16) {
#pragma unroll
    for (int j = 0; j < 4; ++j) {
      int t = tid + j * 256;
      int kk = t & 15, row = t >> 4;
      int gr = bR + row, gk = k0 + kk;
      sA[kk][row] = (gr < NNODES && gk < din) ? H[(size_t)gr * ldh + gk] : 0.f;
    }
#pragma unroll
    for (int j = 0; j < 4; ++j) {
      int t = tid + j * 256;
      int kk = t >> 6, c = t & 63;
      int gc = bC + c, gk = k0 + kk;
      float w = 0.f;
      if (gk < din)
        w = (gc < dout) ? W1[(size_t)gk * dout + gc]
                        : W1[(size_t)(din + gk) * dout + (gc - dout)];
      sW[kk][c] = w;
    }
    __syncthreads();
#pragma unroll
    for (int kk = 0; kk < 16; ++kk) {
      float a[4], w[4];
#pragma unroll
      for (int i = 0; i < 4; ++i) a[i] = sA[kk][ty + 16 * i];
#pragma unroll
      for (int j = 0; j < 4; ++j) w[j] = sW[kk][tx + 16 * j];
#pragma unroll
      for (int i = 0; i < 4; ++i)
#pragma unroll
        for (int j = 0; j < 4; ++j) acc[i][j] += a[i] * w[j];
    }
    __syncthreads();
  }
#pragma unroll
  for (int i = 0; i < 4; ++i) {
    int gr = bR + ty + 16 * i;
    if (gr >= NNODES) continue;
#pragma unroll
    for (int j = 0; j < 4; ++j) {
      int gc = bC + tx + 16 * j;
      float bias = (gc < dout) ? b1[gc] : 0.f;
      AV[(size_t)gr * NN2 + gc] = acc[i][j] + bias;
    }
  }
}

// ---------------- edge kernel: R = relu(A[dst]+V[src]-V[dst]); S[dst] += R@W2 ----
template <int D>
__global__ __launch_bounds__(256) void edge_kernel(
    const float* __restrict__ AV, const int* __restrict__ esrc,
    const int* __restrict__ edst, const float* __restrict__ W2,
    float* __restrict__ S) {
  constexpr int KB = 8;
  constexpr int NJ = D / 64;
  __shared__ float R[32 * D];
  __shared__ float sW[KB * D];
  __shared__ int sdst[32], ssrc[32];
  int tid = threadIdx.x;
  int e0 = blockIdx.x * 32;
  if (tid < 32) {
    sdst[tid] = edst[e0 + tid];
    ssrc[tid] = esrc[e0 + tid];
  }
  __syncthreads();
  // build R tile [32][D]
  constexpr int Q = D / 4;
  for (int t = tid; t < 32 * Q; t += 256) {
    int e = t / Q, q = t % Q;
    int ds = sdst[e], sr = ssrc[e];
    const float4 a  = *(const float4*)(AV + (size_t)ds * 2 * D + 4 * q);
    const float4 vs = *(const float4*)(AV + (size_t)sr * 2 * D + D + 4 * q);
    const float4 vd = *(const float4*)(AV + (size_t)ds * 2 * D + D + 4 * q);
    float4 r;
    r.x = fmaxf(a.x + vs.x - vd.x, 0.f);
    r.y = fmaxf(a.y + vs.y - vd.y, 0.f);
    r.z = fmaxf(a.z + vs.z - vd.z, 0.f);
    r.w = fmaxf(a.w + vs.w - vd.w, 0.f);
    *(float4*)(R + e * D + 4 * q) = r;
  }
  __syncthreads();
  float acc[8][NJ];
#pragma unroll
  for (int i = 0; i < 8; ++i)
#pragma unroll
    for (int j = 0; j < NJ; ++j) acc[i][j] = 0.f;
  int eg = tid >> 6, cg = tid & 63;
  for (int kb = 0; kb < D; kb += KB) {
    for (int t = tid; t < KB * D; t += 256) {
      int kk = t / D, c = t % D;
      sW[t] = W2[(size_t)(kb + kk) * D + c];
    }
    __syncthreads();
#pragma unroll
    for (int kk = 0; kk < KB; ++kk) {
      float rv[8];
#pragma unroll
      for (int i = 0; i < 8; ++i) rv[i] = R[(eg * 8 + i) * D + kb + kk];
#pragma unroll
      for (int j = 0; j < NJ; ++j) {
        float w = sW[kk * D + cg + 64 * j];
#pragma unroll
        for (int i = 0; i < 8; ++i) acc[i][j] += rv[i] * w;
      }
    }
    __syncthreads();
  }
#pragma unroll
  for (int i = 0; i < 8; ++i) {
    int node = sdst[eg * 8 + i];
    float* Srow = S + (size_t)node * D;
#pragma unroll
    for (int j = 0; j < NJ; ++j) atomicAdd(Srow + cg + 64 * j, acc[i][j]);
  }
}

// ---------------- column stats of Y = (cnt>0 ? S/cnt + b2 : 0) ----------------
__global__ __launch_bounds__(256) void colstats_kernel(
    const float* __restrict__ S, const int* __restrict__ cnt,
    const float* __restrict__ b2, int dout, float* __restrict__ stats,
    int rows_per_block) {
  int c = blockIdx.x * blockDim.x + threadIdx.x;
  if (c >= dout) return;
  int r0 = blockIdx.y * rows_per_block;
  int r1 = min(r0 + rows_per_block, NNODES);
  float bias = b2[c];
  float s = 0.f, s2 = 0.f;
  for (int r = r0; r < r1; ++r) {
    int ct = cnt[r];
    float y = (ct > 0) ? (S[(size_t)r * dout + c] / (float)ct + bias) : 0.f;
    s += y;
    s2 += y * y;
  }
  atomicAdd(&stats[c], s);
  atomicAdd(&stats[dout + c], s2);
}

// ---------------- BN(train) + ReLU -> H (layers 1-4) ----------------
__global__ __launch_bounds__(256) void bn_relu_kernel(
    const float* __restrict__ S, const int* __restrict__ cnt,
    const float* __restrict__ b2, const float* __restrict__ stats,
    const float* __restrict__ g, const float* __restrict__ bb, int dout,
    float* __restrict__ Hout) {
  size_t idx = (size_t)blockIdx.x * blockDim.x + threadIdx.x;
  size_t total = (size_t)NNODES * dout;
  if (idx >= total) return;
  int c = (int)(idx % dout);
  int r = (int)(idx / dout);
  float mu = stats[c] * (1.0f / NNODES);
  float var = stats[dout + c] * (1.0f / NNODES) - mu * mu;
  int ct = cnt[r];
  float y = (ct > 0) ? (S[idx] / (float)ct + b2[c]) : 0.f;
  float v = g[c] * (y - mu) * rsqrtf(var + 1e-5f) + bb[c];
  Hout[idx] = fmaxf(v, 0.f);
}

// ---------------- layer 5: mean + b2 only -> d_out ----------------
__global__ __launch_bounds__(256) void mean_only_kernel(
    const float* __restrict__ S, const int* __restrict__ cnt,
    const float* __restrict__ b2, int dout, float* __restrict__ out) {
  size_t idx = (size_t)blockIdx.x * blockDim.x + threadIdx.x;
  size_t total = (size_t)NNODES * dout;
  if (idx >= total) return;
  int c = (int)(idx % dout);
  int r = (int)(idx / dout);
  int ct = cnt[r];
  out[idx] = (ct > 0) ? (S[idx] / (float)ct + b2[c]) : 0.f;
}

static void launch_edge(int dout, const float* AV, const int* esrc,
                        const int* edst, const float* W2, float* S,
                        hipStream_t st) {
  dim3 grid(NEDGES / 32);
  switch (dout) {
    case 64:
      hipLaunchKernelGGL((edge_kernel<64>), grid, dim3(256), 0, st, AV, esrc, edst, W2, S);
      break;
    case 128:
      hipLaunchKernelGGL((edge_kernel<128>), grid, dim3(256), 0, st, AV, esrc, edst, W2, S);
      break;
    case 256:
      hipLaunchKernelGGL((edge_kernel<256>), grid, dim3(256), 0, st, AV, esrc, edst, W2, S);
      break;
    case 512:
      hipLaunchKernelGGL((edge_kernel<512>), grid, dim3(256), 0, st, AV, esrc, edst, W2, S);
      break;
  }
}

extern "C" void kernel_launch(void* const* d_in, const int* in_sizes, int n_in,
                              void* d_out, int out_size, void* d_ws,
                              size_t ws_size, hipStream_t stream) {
  const float* x = (const float*)d_in[0];
  const int* edge_index = (const int*)d_in[1];
  const int* esrc = edge_index;            // edge_index[0]
  const int* edst = edge_index + NEDGES;   // edge_index[1]

  const float* gw1[5] = {(const float*)d_in[3],  (const float*)d_in[7],
                         (const float*)d_in[11], (const float*)d_in[15],
                         (const float*)d_in[19]};
  const float* gb1[5] = {(const float*)d_in[4],  (const float*)d_in[8],
                         (const float*)d_in[12], (const float*)d_in[16],
                         (const float*)d_in[20]};
  const float* gw2[5] = {(const float*)d_in[5],  (const float*)d_in[9],
                         (const float*)d_in[13], (const float*)d_in[17],
                         (const float*)d_in[21]};
  const float* gb2[5] = {(const float*)d_in[6],  (const float*)d_in[10],
                         (const float*)d_in[14], (const float*)d_in[18],
                         (const float*)d_in[22]};
  const float* ng[4] = {(const float*)d_in[23], (const float*)d_in[25],
                        (const float*)d_in[27], (const float*)d_in[29]};
  const float* nb[4] = {(const float*)d_in[24], (const float*)d_in[26],
                        (const float*)d_in[28], (const float*)d_in[30]};

  // workspace layout (floats)
  float* H = (float*)d_ws;                    // N x 256 (embed uses stride 200)
  float* AV = H + (size_t)NNODES * 256;       // N x 1024
  float* S = AV + (size_t)NNODES * 1024;      // N x 512
  int* cnt = (int*)(S + (size_t)NNODES * 512);
  float* stats = (float*)(cnt + NNODES);      // 2 x 512

  const int dins[5] = {200, 64, 128, 256, 256};
  const int douts[5] = {64, 128, 256, 256, 512};

  hipMemsetAsync(cnt, 0, NNODES * sizeof(int), stream);
  count_kernel<<<(NEDGES + 255) / 256, 256, 0, stream>>>(edst, cnt);
  embed_kernel<<<(NNODES + 255) / 256, 256, 0, stream>>>(x, H);

  int ldh = 200;
  for (int L = 0; L < 5; ++L) {
    int din = dins[L], dout = douts[L];
    dim3 ggrid(2 * dout / 64, (NNODES + 63) / 64);
    node_gemm_kernel<<<ggrid, 256, 0, stream>>>(H, ldh, din, dout, gw1[L], gb1[L], AV);
    hipMemsetAsync(S, 0, (size_t)NNODES * dout * sizeof(float), stream);
    launch_edge(dout, AV, esrc, edst, gw2[L], S, stream);
    if (L < 4) {
      hipMemsetAsync(stats, 0, 2 * dout * sizeof(float), stream);
      dim3 cgrid((dout + 255) / 256, 80);
      colstats_kernel<<<cgrid, 256, 0, stream>>>(S, cnt, gb2[L], dout, stats, 250);
      size_t total = (size_t)NNODES * dout;
      bn_relu_kernel<<<(total + 255) / 256, 256, 0, stream>>>(
          S, cnt, gb2[L], stats, ng[L], nb[L], dout, H);
      ldh = dout;
    } else {
      size_t total = (size_t)NNODES * dout;
      mean_only_kernel<<<(total + 255) / 256, 256, 0, stream>>>(
          S, cnt, gb2[L], dout, (float*)d_out);
    }
  }
}

// Round 2
// 1528.991 us; speedup vs baseline: 7.4467x; 7.4467x over previous
//
#include <hip/hip_runtime.h>
#include <math.h>

#define NNODES 20000
#define NEDGES 320000

// ---------------- embed: NeRF positional encoding ----------------
__global__ __launch_bounds__(256) void embed_kernel(const float* __restrict__ x,
                                                    float* __restrict__ h) {
  int n = blockIdx.x * blockDim.x + threadIdx.x;
  if (n >= NNODES) return;
  const float* xr = x + (size_t)n * 20;
  float* hr = h + (size_t)n * 200;
#pragma unroll
  for (int g = 0; g < 3; ++g) {
    float v0 = xr[g * 3 + 0], v1 = xr[g * 3 + 1], v2 = xr[g * 3 + 2];
    float* o = hr + g * 63;
    o[0] = v0; o[1] = v1; o[2] = v2;
    float f = 1.0f;
    for (int fr = 0; fr < 10; ++fr) {
      float s0, c0, s1, c1, s2, c2;
      sincosf(v0 * f, &s0, &c0);
      sincosf(v1 * f, &s1, &c1);
      sincosf(v2 * f, &s2, &c2);
      int base = 3 + fr * 6;
      o[base + 0] = s0; o[base + 1] = s1; o[base + 2] = s2;
      o[base + 3] = c0; o[base + 4] = c1; o[base + 5] = c2;
      f *= 2.0f;
    }
  }
  for (int j = 0; j < 11; ++j) hr[189 + j] = xr[9 + j];
}

// ---------------- per-node in-degree counts (layer-invariant) ----------------
__global__ __launch_bounds__(256) void count_kernel(const int* __restrict__ edst,
                                                    int* __restrict__ cnt) {
  int e = blockIdx.x * blockDim.x + threadIdx.x;
  if (e < NEDGES) atomicAdd(&cnt[edst[e]], 1);
}

// ---------------- exclusive scan of cnt -> rowptr (single block) ----------------
__global__ __launch_bounds__(256) void scan_kernel(const int* __restrict__ cnt,
                                                   int* __restrict__ rowptr,
                                                   int* __restrict__ head) {
  __shared__ int buf[256];
  __shared__ int carry;
  if (threadIdx.x == 0) carry = 0;
  __syncthreads();
  for (int base = 0; base < NNODES; base += 256) {
    int i = base + threadIdx.x;
    int v = (i < NNODES) ? cnt[i] : 0;
    buf[threadIdx.x] = v;
    __syncthreads();
#pragma unroll
    for (int off = 1; off < 256; off <<= 1) {
      int t = (threadIdx.x >= off) ? buf[threadIdx.x - off] : 0;
      __syncthreads();
      buf[threadIdx.x] += t;
      __syncthreads();
    }
    int incl = buf[threadIdx.x];
    int excl = carry + incl - v;
    if (i < NNODES) {
      rowptr[i] = excl;
      head[i] = excl;
    }
    __syncthreads();
    if (threadIdx.x == 255) carry += buf[255];
    __syncthreads();
  }
  if (threadIdx.x == 0) rowptr[NNODES] = carry;
}

// ---------------- scatter edges into CSR buckets ----------------
__global__ __launch_bounds__(256) void scatter_kernel(const int* __restrict__ esrc,
                                                      const int* __restrict__ edst,
                                                      int* __restrict__ head,
                                                      int* __restrict__ csr_src) {
  int e = blockIdx.x * blockDim.x + threadIdx.x;
  if (e < NEDGES) {
    int pos = atomicAdd(&head[edst[e]], 1);
    csr_src[pos] = esrc[e];
  }
}

// ---------------- node GEMM: AV[n, 0:dout]=h@W1a+b1, AV[n, dout:2dout]=h@W1b ----
__global__ __launch_bounds__(256) void node_gemm_kernel(
    const float* __restrict__ H, int ldh, int din, int dout,
    const float* __restrict__ W1, const float* __restrict__ b1,
    float* __restrict__ AV) {
  __shared__ float sA[16][65];
  __shared__ float sW[16][64];
  const int NN2 = 2 * dout;
  int tid = threadIdx.x;
  int bR = blockIdx.y * 64, bC = blockIdx.x * 64;
  int ty = tid / 16, tx = tid % 16;
  float acc[4][4] = {{0.f}};
  for (int k0 = 0; k0 < din; k0 += 16) {
#pragma unroll
    for (int j = 0; j < 4; ++j) {
      int t = tid + j * 256;
      int kk = t & 15, row = t >> 4;
      int gr = bR + row, gk = k0 + kk;
      sA[kk][row] = (gr < NNODES && gk < din) ? H[(size_t)gr * ldh + gk] : 0.f;
    }
#pragma unroll
    for (int j = 0; j < 4; ++j) {
      int t = tid + j * 256;
      int kk = t >> 6, c = t & 63;
      int gc = bC + c, gk = k0 + kk;
      float w = 0.f;
      if (gk < din)
        w = (gc < dout) ? W1[(size_t)gk * dout + gc]
                        : W1[(size_t)(din + gk) * dout + (gc - dout)];
      sW[kk][c] = w;
    }
    __syncthreads();
#pragma unroll
    for (int kk = 0; kk < 16; ++kk) {
      float a[4], w[4];
#pragma unroll
      for (int i = 0; i < 4; ++i) a[i] = sA[kk][ty + 16 * i];
#pragma unroll
      for (int j = 0; j < 4; ++j) w[j] = sW[kk][tx + 16 * j];
#pragma unroll
      for (int i = 0; i < 4; ++i)
#pragma unroll
        for (int j = 0; j < 4; ++j) acc[i][j] += a[i] * w[j];
    }
    __syncthreads();
  }
#pragma unroll
  for (int i = 0; i < 4; ++i) {
    int gr = bR + ty + 16 * i;
    if (gr >= NNODES) continue;
#pragma unroll
    for (int j = 0; j < 4; ++j) {
      int gc = bC + tx + 16 * j;
      float bias = (gc < dout) ? b1[gc] : 0.f;
      AV[(size_t)gr * NN2 + gc] = acc[i][j] + bias;
    }
  }
}

// ------- edge aggregation (gather): Y[n] = (1/cnt) * sum_e relu(A[n]-V[n]+V[src_e]) -------
template <int D>
__global__ __launch_bounds__(256) void edge_agg_kernel(
    const float* __restrict__ AV, const int* __restrict__ rowptr,
    const int* __restrict__ csr_src, float* __restrict__ Y) {
  constexpr int TPN = D / 4;        // threads per node (each owns 4 cols)
  constexpr int NPB = 256 / TPN;    // nodes per block
  int tid = threadIdx.x;
  int ln = tid % TPN;
  int sn = tid / TPN;
  int node = blockIdx.x * NPB + sn;
  if (node >= NNODES) return;
  int c = ln * 4;
  const float* Arow = AV + (size_t)node * 2 * D;
  float4 a = *(const float4*)(Arow + c);
  float4 vd = *(const float4*)(Arow + D + c);
  float4 ad;
  ad.x = a.x - vd.x; ad.y = a.y - vd.y; ad.z = a.z - vd.z; ad.w = a.w - vd.w;
  float4 acc = {0.f, 0.f, 0.f, 0.f};
  int e0 = rowptr[node], e1 = rowptr[node + 1];
  int e = e0;
  for (; e + 1 < e1; e += 2) {
    int s0 = csr_src[e], s1 = csr_src[e + 1];
    float4 v0 = *(const float4*)(AV + (size_t)s0 * 2 * D + D + c);
    float4 v1 = *(const float4*)(AV + (size_t)s1 * 2 * D + D + c);
    acc.x += fmaxf(ad.x + v0.x, 0.f) + fmaxf(ad.x + v1.x, 0.f);
    acc.y += fmaxf(ad.y + v0.y, 0.f) + fmaxf(ad.y + v1.y, 0.f);
    acc.z += fmaxf(ad.z + v0.z, 0.f) + fmaxf(ad.z + v1.z, 0.f);
    acc.w += fmaxf(ad.w + v0.w, 0.f) + fmaxf(ad.w + v1.w, 0.f);
  }
  if (e < e1) {
    int s0 = csr_src[e];
    float4 v0 = *(const float4*)(AV + (size_t)s0 * 2 * D + D + c);
    acc.x += fmaxf(ad.x + v0.x, 0.f);
    acc.y += fmaxf(ad.y + v0.y, 0.f);
    acc.z += fmaxf(ad.z + v0.z, 0.f);
    acc.w += fmaxf(ad.w + v0.w, 0.f);
  }
  float inv = (e1 > e0) ? 1.f / (float)(e1 - e0) : 0.f;
  float4 out;
  out.x = acc.x * inv; out.y = acc.y * inv; out.z = acc.z * inv; out.w = acc.w * inv;
  *(float4*)(Y + (size_t)node * D + c) = out;
}

// ---------------- gemm2: out = Y @ W2 (+ b2 masked by cnt>0) ----------------
__global__ __launch_bounds__(256) void gemm2_kernel(
    const float* __restrict__ Y, int K, int Ncol,
    const float* __restrict__ W2, const float* __restrict__ b2,
    const int* __restrict__ cnt, float* __restrict__ out) {
  __shared__ float sA[16][65];
  __shared__ float sW[16][64];
  int tid = threadIdx.x;
  int bR = blockIdx.y * 64, bC = blockIdx.x * 64;
  int ty = tid / 16, tx = tid % 16;
  float acc[4][4] = {{0.f}};
  for (int k0 = 0; k0 < K; k0 += 16) {
#pragma unroll
    for (int j = 0; j < 4; ++j) {
      int t = tid + j * 256;
      int kk = t & 15, row = t >> 4;
      int gr = bR + row, gk = k0 + kk;
      sA[kk][row] = (gr < NNODES) ? Y[(size_t)gr * K + gk] : 0.f;
    }
#pragma unroll
    for (int j = 0; j < 4; ++j) {
      int t = tid + j * 256;
      int kk = t >> 6, c = t & 63;
      sW[kk][c] = W2[(size_t)(k0 + kk) * Ncol + bC + c];
    }
    __syncthreads();
#pragma unroll
    for (int kk = 0; kk < 16; ++kk) {
      float a[4], w[4];
#pragma unroll
      for (int i = 0; i < 4; ++i) a[i] = sA[kk][ty + 16 * i];
#pragma unroll
      for (int j = 0; j < 4; ++j) w[j] = sW[kk][tx + 16 * j];
#pragma unroll
      for (int i = 0; i < 4; ++i)
#pragma unroll
        for (int j = 0; j < 4; ++j) acc[i][j] += a[i] * w[j];
    }
    __syncthreads();
  }
#pragma unroll
  for (int i = 0; i < 4; ++i) {
    int gr = bR + ty + 16 * i;
    if (gr >= NNODES) continue;
    int ct = cnt[gr];
#pragma unroll
    for (int j = 0; j < 4; ++j) {
      int gc = bC + tx + 16 * j;
      float v = (ct > 0) ? (acc[i][j] + b2[gc]) : 0.f;
      out[(size_t)gr * Ncol + gc] = v;
    }
  }
}

// ---------------- column stats of S ----------------
__global__ __launch_bounds__(256) void colstats_kernel(
    const float* __restrict__ S, int dout, float* __restrict__ stats,
    int rows_per_block) {
  int c = blockIdx.x * blockDim.x + threadIdx.x;
  if (c >= dout) return;
  int r0 = blockIdx.y * rows_per_block;
  int r1 = min(r0 + rows_per_block, NNODES);
  float s = 0.f, s2 = 0.f;
  for (int r = r0; r < r1; ++r) {
    float y = S[(size_t)r * dout + c];
    s += y;
    s2 += y * y;
  }
  atomicAdd(&stats[c], s);
  atomicAdd(&stats[dout + c], s2);
}

// ---------------- BN(train) + ReLU -> H ----------------
__global__ __launch_bounds__(256) void bn_relu_kernel(
    const float* __restrict__ S, const float* __restrict__ stats,
    const float* __restrict__ g, const float* __restrict__ bb, int dout,
    float* __restrict__ Hout) {
  size_t idx = (size_t)blockIdx.x * blockDim.x + threadIdx.x;
  size_t total = (size_t)NNODES * dout;
  if (idx >= total) return;
  int c = (int)(idx % dout);
  float mu = stats[c] * (1.0f / NNODES);
  float var = stats[dout + c] * (1.0f / NNODES) - mu * mu;
  float y = S[idx];
  float v = g[c] * (y - mu) * rsqrtf(var + 1e-5f) + bb[c];
  Hout[idx] = fmaxf(v, 0.f);
}

static void launch_edge_agg(int dout, const float* AV, const int* rowptr,
                            const int* csr_src, float* Y, hipStream_t st) {
  switch (dout) {
    case 64: {
      dim3 grid((NNODES + 15) / 16);
      hipLaunchKernelGGL((edge_agg_kernel<64>), grid, dim3(256), 0, st, AV, rowptr, csr_src, Y);
      break;
    }
    case 128: {
      dim3 grid((NNODES + 7) / 8);
      hipLaunchKernelGGL((edge_agg_kernel<128>), grid, dim3(256), 0, st, AV, rowptr, csr_src, Y);
      break;
    }
    case 256: {
      dim3 grid((NNODES + 3) / 4);
      hipLaunchKernelGGL((edge_agg_kernel<256>), grid, dim3(256), 0, st, AV, rowptr, csr_src, Y);
      break;
    }
    case 512: {
      dim3 grid((NNODES + 1) / 2);
      hipLaunchKernelGGL((edge_agg_kernel<512>), grid, dim3(256), 0, st, AV, rowptr, csr_src, Y);
      break;
    }
  }
}

extern "C" void kernel_launch(void* const* d_in, const int* in_sizes, int n_in,
                              void* d_out, int out_size, void* d_ws,
                              size_t ws_size, hipStream_t stream) {
  const float* x = (const float*)d_in[0];
  const int* edge_index = (const int*)d_in[1];
  const int* esrc = edge_index;            // edge_index[0]
  const int* edst = edge_index + NEDGES;   // edge_index[1]

  const float* gw1[5] = {(const float*)d_in[3],  (const float*)d_in[7],
                         (const float*)d_in[11], (const float*)d_in[15],
                         (const float*)d_in[19]};
  const float* gb1[5] = {(const float*)d_in[4],  (const float*)d_in[8],
                         (const float*)d_in[12], (const float*)d_in[16],
                         (const float*)d_in[20]};
  const float* gw2[5] = {(const float*)d_in[5],  (const float*)d_in[9],
                         (const float*)d_in[13], (const float*)d_in[17],
                         (const float*)d_in[21]};
  const float* gb2[5] = {(const float*)d_in[6],  (const float*)d_in[10],
                         (const float*)d_in[14], (const float*)d_in[18],
                         (const float*)d_in[22]};
  const float* ng[4] = {(const float*)d_in[23], (const float*)d_in[25],
                        (const float*)d_in[27], (const float*)d_in[29]};
  const float* nb[4] = {(const float*)d_in[24], (const float*)d_in[26],
                        (const float*)d_in[28], (const float*)d_in[30]};

  // workspace layout (floats)
  float* B1 = (float*)d_ws;                      // N x 512  (H and Y share)
  float* AV = B1 + (size_t)NNODES * 512;         // N x 1024
  float* S  = AV + (size_t)NNODES * 1024;        // N x 256  (layers 1-4 only)
  int* cnt = (int*)(S + (size_t)NNODES * 256);   // N
  int* rowptr = cnt + NNODES;                    // N+1
  int* head = rowptr + NNODES + 1;               // N
  int* csr_src = head + NNODES;                  // E
  float* stats = (float*)(csr_src + NEDGES);     // 2 x 512

  const int dins[5] = {200, 64, 128, 256, 256};
  const int douts[5] = {64, 128, 256, 256, 512};

  hipMemsetAsync(cnt, 0, NNODES * sizeof(int), stream);
  count_kernel<<<(NEDGES + 255) / 256, 256, 0, stream>>>(edst, cnt);
  scan_kernel<<<1, 256, 0, stream>>>(cnt, rowptr, head);
  scatter_kernel<<<(NEDGES + 255) / 256, 256, 0, stream>>>(esrc, edst, head, csr_src);
  embed_kernel<<<(NNODES + 255) / 256, 256, 0, stream>>>(x, B1);

  int ldh = 200;
  for (int L = 0; L < 5; ++L) {
    int din = dins[L], dout = douts[L];
    // AV = [H@W1a + b1 | H@W1b]
    dim3 ggrid(2 * dout / 64, (NNODES + 63) / 64);
    node_gemm_kernel<<<ggrid, 256, 0, stream>>>(B1, ldh, din, dout, gw1[L], gb1[L], AV);
    // Y = scatter-mean of relu messages (gather over CSR), into B1
    launch_edge_agg(dout, AV, rowptr, csr_src, B1, stream);
    // S = Y @ W2 + b2 (cnt-masked)
    float* dst = (L < 4) ? S : (float*)d_out;
    dim3 g2(dout / 64, (NNODES + 63) / 64);
    gemm2_kernel<<<g2, 256, 0, stream>>>(B1, dout, dout, gw2[L], gb2[L], cnt, dst);
    if (L < 4) {
      hipMemsetAsync(stats, 0, 2 * dout * sizeof(float), stream);
      dim3 cgrid((dout + 255) / 256, 80);
      colstats_kernel<<<cgrid, 256, 0, stream>>>(S, dout, stats, 250);
      size_t total = (size_t)NNODES * dout;
      bn_relu_kernel<<<(total + 255) / 256, 256, 0, stream>>>(
          S, stats, ng[L], nb[L], dout, B1);
      ldh = dout;
    }
  }
}

// Round 3
// 848.522 us; speedup vs baseline: 13.4185x; 1.8019x over previous
//
#include <hip/hip_runtime.h>
#include <math.h>

#define NNODES 20000
#define NEDGES 320000

typedef __bf16 bf16x8 __attribute__((ext_vector_type(8)));
typedef float f32x4 __attribute__((ext_vector_type(4)));
typedef unsigned short u16x4 __attribute__((ext_vector_type(4)));

__device__ inline unsigned short f2bf(float x) {
  union { float f; unsigned int u; } q;
  q.f = x;
  unsigned int u = q.u;
  unsigned int r = (u + 0x7fffu + ((u >> 16) & 1u)) >> 16;
  return (unsigned short)r;
}

// ---------------- embed: NeRF positional encoding -> bf16, stride 224, zero-pad ----
__global__ __launch_bounds__(256) void embed_kernel(const float* __restrict__ x,
                                                    unsigned short* __restrict__ h) {
  int n = blockIdx.x * blockDim.x + threadIdx.x;
  if (n >= NNODES) return;
  const float* xr = x + (size_t)n * 20;
  unsigned short* hr = h + (size_t)n * 224;
#pragma unroll
  for (int g = 0; g < 3; ++g) {
    float v0 = xr[g * 3 + 0], v1 = xr[g * 3 + 1], v2 = xr[g * 3 + 2];
    unsigned short* o = hr + g * 63;
    o[0] = f2bf(v0); o[1] = f2bf(v1); o[2] = f2bf(v2);
    float f = 1.0f;
    for (int fr = 0; fr < 10; ++fr) {
      float s0, c0, s1, c1, s2, c2;
      sincosf(v0 * f, &s0, &c0);
      sincosf(v1 * f, &s1, &c1);
      sincosf(v2 * f, &s2, &c2);
      int base = 3 + fr * 6;
      o[base + 0] = f2bf(s0); o[base + 1] = f2bf(s1); o[base + 2] = f2bf(s2);
      o[base + 3] = f2bf(c0); o[base + 4] = f2bf(c1); o[base + 5] = f2bf(c2);
      f *= 2.0f;
    }
  }
  for (int j = 0; j < 11; ++j) hr[189 + j] = f2bf(xr[9 + j]);
  for (int j = 200; j < 224; ++j) hr[j] = 0;
}

// ---------------- per-node in-degree counts ----------------
__global__ __launch_bounds__(256) void count_kernel(const int* __restrict__ edst,
                                                    int* __restrict__ cnt) {
  int e = blockIdx.x * blockDim.x + threadIdx.x;
  if (e < NEDGES) atomicAdd(&cnt[edst[e]], 1);
}

// ---------------- chunked exclusive scan (single block, few barriers) ----------------
__global__ __launch_bounds__(256) void scan_kernel(const int* __restrict__ cnt,
                                                   int* __restrict__ rowptr,
                                                   int* __restrict__ head) {
  __shared__ int tsum[256];
  const int CH = (NNODES + 255) / 256;  // 79
  int t = threadIdx.x;
  int i0 = t * CH;
  int i1 = min(i0 + CH, NNODES);
  int s = 0;
  for (int i = i0; i < i1; ++i) s += cnt[i];
  tsum[t] = s;
  __syncthreads();
  for (int off = 1; off < 256; off <<= 1) {
    int v = (t >= off) ? tsum[t - off] : 0;
    __syncthreads();
    tsum[t] += v;
    __syncthreads();
  }
  int run = tsum[t] - s;  // exclusive prefix of this chunk
  for (int i = i0; i < i1; ++i) {
    rowptr[i] = run;
    head[i] = run;
    run += cnt[i];
  }
  if (t == 255) rowptr[NNODES] = run;
}

// ---------------- scatter edges into CSR buckets ----------------
__global__ __launch_bounds__(256) void scatter_kernel(const int* __restrict__ esrc,
                                                      const int* __restrict__ edst,
                                                      int* __restrict__ head,
                                                      int* __restrict__ csr_src) {
  int e = blockIdx.x * blockDim.x + threadIdx.x;
  if (e < NEDGES) {
    int pos = atomicAdd(&head[edst[e]], 1);
    csr_src[pos] = esrc[e];
  }
}

// ---------------- weight prep: Wt1[c][k] (bf16), c in [0,2*dout), k in [0,Kpad) ----
__global__ __launch_bounds__(256) void transpose_w1_kernel(
    const float* __restrict__ W1, int din, int dout, int Kpad,
    unsigned short* __restrict__ Wt1) {
  int idx = blockIdx.x * 256 + threadIdx.x;
  int total = 2 * dout * Kpad;
  if (idx >= total) return;
  int c = idx / Kpad, k = idx % Kpad;
  float v = 0.f;
  if (k < din)
    v = (c < dout) ? W1[(size_t)k * dout + c]
                   : W1[(size_t)(din + k) * dout + (c - dout)];
  Wt1[idx] = f2bf(v);
}

// ---------------- weight prep: Wt2[n][k] = W2[k][n] (bf16) ----------------
__global__ __launch_bounds__(256) void transpose_w2_kernel(
    const float* __restrict__ W2, int d, unsigned short* __restrict__ Wt2) {
  int idx = blockIdx.x * 256 + threadIdx.x;
  int total = d * d;
  if (idx >= total) return;
  int n = idx / d, k = idx % d;
  Wt2[idx] = f2bf(W2[(size_t)k * d + n]);
}

// ---------------- MFMA GEMM: C[M x Ncol] = A[M x K](bf16) @ Bt[Ncol x K]^T ----
// EPI 0: C = acc + (col<dhalf ? bias[col] : 0)          (gemm1 -> AV, fp32)
// EPI 1: C = cnt[row]>0 ? acc + bias[col] : 0           (gemm2 -> S/out, fp32)
template <int EPI>
__global__ __launch_bounds__(256) void mfma_gemm_kernel(
    const unsigned short* __restrict__ A, int lda, int K,
    const unsigned short* __restrict__ Bt, int Ncol, int dhalf,
    const float* __restrict__ bias, const int* __restrict__ cnt,
    float* __restrict__ C) {
  __shared__ unsigned short sA[128 * 40];
  __shared__ unsigned short sB[64 * 40];
  int tid = threadIdx.x;
  int bR = blockIdx.y * 128, bC = blockIdx.x * 64;
  int wid = tid >> 6, lane = tid & 63;
  int wr = wid >> 1, wc = wid & 1;
  int lr = lane & 15, lg = lane >> 4;

  f32x4 acc[4][2];
#pragma unroll
  for (int fr = 0; fr < 4; ++fr)
#pragma unroll
    for (int fc = 0; fc < 2; ++fc) acc[fr][fc] = f32x4{0.f, 0.f, 0.f, 0.f};

  for (int k0 = 0; k0 < K; k0 += 32) {
    // stage A tile [128][32]
#pragma unroll
    for (int rep = 0; rep < 2; ++rep) {
      int idx = tid + rep * 256;
      int row = idx >> 2, kq = (idx & 3) * 8;
      int gr = bR + row;
      bf16x8 v;
      if (gr < NNODES) {
        v = *(const bf16x8*)(A + (size_t)gr * lda + k0 + kq);
      } else {
#pragma unroll
        for (int i = 0; i < 8; ++i) v[i] = (__bf16)0.f;
      }
      *(bf16x8*)(sA + row * 40 + kq) = v;
    }
    // stage B tile [64][32]
    {
      int n = tid >> 2, kq = (tid & 3) * 8;
      bf16x8 v = *(const bf16x8*)(Bt + (size_t)(bC + n) * K + k0 + kq);
      *(bf16x8*)(sB + n * 40 + kq) = v;
    }
    __syncthreads();
    bf16x8 aF[4], bF[2];
#pragma unroll
    for (int fr = 0; fr < 4; ++fr)
      aF[fr] = *(const bf16x8*)(sA + (wr * 64 + fr * 16 + lr) * 40 + lg * 8);
#pragma unroll
    for (int fc = 0; fc < 2; ++fc)
      bF[fc] = *(const bf16x8*)(sB + (wc * 32 + fc * 16 + lr) * 40 + lg * 8);
#pragma unroll
    for (int fr = 0; fr < 4; ++fr)
#pragma unroll
      for (int fc = 0; fc < 2; ++fc)
        acc[fr][fc] = __builtin_amdgcn_mfma_f32_16x16x32_bf16(
            aF[fr], bF[fc], acc[fr][fc], 0, 0, 0);
    __syncthreads();
  }

#pragma unroll
  for (int fr = 0; fr < 4; ++fr) {
#pragma unroll
    for (int j = 0; j < 4; ++j) {
      int gr = bR + wr * 64 + fr * 16 + lg * 4 + j;
      if (gr >= NNODES) continue;
      int ct = (EPI == 1) ? cnt[gr] : 1;
#pragma unroll
      for (int fc = 0; fc < 2; ++fc) {
        int gc = bC + wc * 32 + fc * 16 + lr;
        float v = acc[fr][fc][j];
        if (EPI == 0) {
          if (gc < dhalf) v += bias[gc];
        } else {
          v = (ct > 0) ? (v + bias[gc]) : 0.f;
        }
        C[(size_t)gr * Ncol + gc] = v;
      }
    }
  }
}

// ------- edge aggregation (gather): Y[n] = (1/cnt) * sum_e relu(A[n]-V[n]+V[src_e]) -------
template <int D>
__global__ __launch_bounds__(256) void edge_agg_kernel(
    const float* __restrict__ AV, const int* __restrict__ rowptr,
    const int* __restrict__ csr_src, unsigned short* __restrict__ Y) {
  constexpr int TPN = D / 4;        // threads per node (each owns 4 cols)
  constexpr int NPB = 256 / TPN;    // nodes per block
  int tid = threadIdx.x;
  int ln = tid % TPN;
  int sn = tid / TPN;
  int node = blockIdx.x * NPB + sn;
  if (node >= NNODES) return;
  int c = ln * 4;
  const float* Arow = AV + (size_t)node * 2 * D;
  float4 a = *(const float4*)(Arow + c);
  float4 vd = *(const float4*)(Arow + D + c);
  float4 ad;
  ad.x = a.x - vd.x; ad.y = a.y - vd.y; ad.z = a.z - vd.z; ad.w = a.w - vd.w;
  float4 acc = {0.f, 0.f, 0.f, 0.f};
  int e0 = rowptr[node], e1 = rowptr[node + 1];
  int e = e0;
  for (; e + 1 < e1; e += 2) {
    int s0 = csr_src[e], s1 = csr_src[e + 1];
    float4 v0 = *(const float4*)(AV + (size_t)s0 * 2 * D + D + c);
    float4 v1 = *(const float4*)(AV + (size_t)s1 * 2 * D + D + c);
    acc.x += fmaxf(ad.x + v0.x, 0.f) + fmaxf(ad.x + v1.x, 0.f);
    acc.y += fmaxf(ad.y + v0.y, 0.f) + fmaxf(ad.y + v1.y, 0.f);
    acc.z += fmaxf(ad.z + v0.z, 0.f) + fmaxf(ad.z + v1.z, 0.f);
    acc.w += fmaxf(ad.w + v0.w, 0.f) + fmaxf(ad.w + v1.w, 0.f);
  }
  if (e < e1) {
    int s0 = csr_src[e];
    float4 v0 = *(const float4*)(AV + (size_t)s0 * 2 * D + D + c);
    acc.x += fmaxf(ad.x + v0.x, 0.f);
    acc.y += fmaxf(ad.y + v0.y, 0.f);
    acc.z += fmaxf(ad.z + v0.z, 0.f);
    acc.w += fmaxf(ad.w + v0.w, 0.f);
  }
  float inv = (e1 > e0) ? 1.f / (float)(e1 - e0) : 0.f;
  u16x4 o;
  o[0] = f2bf(acc.x * inv);
  o[1] = f2bf(acc.y * inv);
  o[2] = f2bf(acc.z * inv);
  o[3] = f2bf(acc.w * inv);
  *(u16x4*)(Y + (size_t)node * D + c) = o;
}

// ---------------- column stats of S ----------------
__global__ __launch_bounds__(256) void colstats_kernel(
    const float* __restrict__ S, int dout, float* __restrict__ stats,
    int rows_per_block) {
  int c = blockIdx.x * blockDim.x + threadIdx.x;
  if (c >= dout) return;
  int r0 = blockIdx.y * rows_per_block;
  int r1 = min(r0 + rows_per_block, NNODES);
  float s = 0.f, s2 = 0.f;
  for (int r = r0; r < r1; ++r) {
    float y = S[(size_t)r * dout + c];
    s += y;
    s2 += y * y;
  }
  atomicAdd(&stats[c], s);
  atomicAdd(&stats[dout + c], s2);
}

// ---------------- BN(train) + ReLU -> H (bf16) ----------------
__global__ __launch_bounds__(256) void bn_relu_kernel(
    const float* __restrict__ S, const float* __restrict__ stats,
    const float* __restrict__ g, const float* __restrict__ bb, int dout,
    unsigned short* __restrict__ Hout) {
  size_t idx = (size_t)blockIdx.x * blockDim.x + threadIdx.x;
  size_t total = (size_t)NNODES * dout;
  if (idx >= total) return;
  int c = (int)(idx % dout);
  float mu = stats[c] * (1.0f / NNODES);
  float var = stats[dout + c] * (1.0f / NNODES) - mu * mu;
  float y = S[idx];
  float v = g[c] * (y - mu) * rsqrtf(var + 1e-5f) + bb[c];
  Hout[idx] = f2bf(fmaxf(v, 0.f));
}

static void launch_edge_agg(int dout, const float* AV, const int* rowptr,
                            const int* csr_src, unsigned short* Y,
                            hipStream_t st) {
  switch (dout) {
    case 64: {
      dim3 grid((NNODES + 15) / 16);
      hipLaunchKernelGGL((edge_agg_kernel<64>), grid, dim3(256), 0, st, AV, rowptr, csr_src, Y);
      break;
    }
    case 128: {
      dim3 grid((NNODES + 7) / 8);
      hipLaunchKernelGGL((edge_agg_kernel<128>), grid, dim3(256), 0, st, AV, rowptr, csr_src, Y);
      break;
    }
    case 256: {
      dim3 grid((NNODES + 3) / 4);
      hipLaunchKernelGGL((edge_agg_kernel<256>), grid, dim3(256), 0, st, AV, rowptr, csr_src, Y);
      break;
    }
    case 512: {
      dim3 grid((NNODES + 1) / 2);
      hipLaunchKernelGGL((edge_agg_kernel<512>), grid, dim3(256), 0, st, AV, rowptr, csr_src, Y);
      break;
    }
  }
}

extern "C" void kernel_launch(void* const* d_in, const int* in_sizes, int n_in,
                              void* d_out, int out_size, void* d_ws,
                              size_t ws_size, hipStream_t stream) {
  const float* x = (const float*)d_in[0];
  const int* edge_index = (const int*)d_in[1];
  const int* esrc = edge_index;            // edge_index[0]
  const int* edst = edge_index + NEDGES;   // edge_index[1]

  const float* gw1[5] = {(const float*)d_in[3],  (const float*)d_in[7],
                         (const float*)d_in[11], (const float*)d_in[15],
                         (const float*)d_in[19]};
  const float* gb1[5] = {(const float*)d_in[4],  (const float*)d_in[8],
                         (const float*)d_in[12], (const float*)d_in[16],
                         (const float*)d_in[20]};
  const float* gw2[5] = {(const float*)d_in[5],  (const float*)d_in[9],
                         (const float*)d_in[13], (const float*)d_in[17],
                         (const float*)d_in[21]};
  const float* gb2[5] = {(const float*)d_in[6],  (const float*)d_in[10],
                         (const float*)d_in[14], (const float*)d_in[18],
                         (const float*)d_in[22]};
  const float* ng[4] = {(const float*)d_in[23], (const float*)d_in[25],
                        (const float*)d_in[27], (const float*)d_in[29]};
  const float* nb[4] = {(const float*)d_in[24], (const float*)d_in[26],
                        (const float*)d_in[28], (const float*)d_in[30]};

  // workspace layout
  float* AV = (float*)d_ws;                              // N x 1024 f32
  float* S = AV + (size_t)NNODES * 1024;                 // N x 256 f32
  unsigned short* Hbf = (unsigned short*)(S + (size_t)NNODES * 256);  // N x 256 bf16 (L1: stride 224)
  unsigned short* Ybf = Hbf + (size_t)NNODES * 256;      // N x 512 bf16
  unsigned short* Wt1 = Ybf + (size_t)NNODES * 512;      // 1024*256 bf16
  unsigned short* Wt2 = Wt1 + 262144;                    // 512*512 bf16
  int* cnt = (int*)(Wt2 + 262144);                       // N
  int* rowptr = cnt + NNODES;                            // N+1
  int* head = rowptr + NNODES + 1;                       // N
  int* csr_src = head + NNODES;                          // E
  float* stats = (float*)(csr_src + NEDGES);             // 2 x 512

  const int dins[5] = {200, 64, 128, 256, 256};
  const int Kpads[5] = {224, 64, 128, 256, 256};
  const int douts[5] = {64, 128, 256, 256, 512};
  const int MBLK = (NNODES + 127) / 128;  // 157

  hipMemsetAsync(cnt, 0, NNODES * sizeof(int), stream);
  count_kernel<<<(NEDGES + 255) / 256, 256, 0, stream>>>(edst, cnt);
  scan_kernel<<<1, 256, 0, stream>>>(cnt, rowptr, head);
  scatter_kernel<<<(NEDGES + 255) / 256, 256, 0, stream>>>(esrc, edst, head, csr_src);
  embed_kernel<<<(NNODES + 255) / 256, 256, 0, stream>>>(x, Hbf);

  int lda = 224;
  for (int L = 0; L < 5; ++L) {
    int din = dins[L], Kp = Kpads[L], dout = douts[L];
    // Wt1 = cat(W1a, W1b)^T in bf16
    int tot1 = 2 * dout * Kp;
    transpose_w1_kernel<<<(tot1 + 255) / 256, 256, 0, stream>>>(gw1[L], din, dout, Kp, Wt1);
    // AV = [H@W1a + b1 | H@W1b]
    dim3 g1(2 * dout / 64, MBLK);
    hipLaunchKernelGGL((mfma_gemm_kernel<0>), g1, dim3(256), 0, stream,
                       Hbf, lda, Kp, Wt1, 2 * dout, dout, gb1[L], (const int*)nullptr, AV);
    // Y = scatter-mean of relu messages (gather over CSR) -> bf16
    launch_edge_agg(dout, AV, rowptr, csr_src, Ybf, stream);
    // Wt2 = W2^T in bf16
    int tot2 = dout * dout;
    transpose_w2_kernel<<<(tot2 + 255) / 256, 256, 0, stream>>>(gw2[L], dout, Wt2);
    // S/out = Y @ W2 + b2 (cnt-masked)
    float* dst = (L < 4) ? S : (float*)d_out;
    dim3 g2(dout / 64, MBLK);
    hipLaunchKernelGGL((mfma_gemm_kernel<1>), g2, dim3(256), 0, stream,
                       Ybf, dout, dout, Wt2, dout, dout, gb2[L], cnt, dst);
    if (L < 4) {
      hipMemsetAsync(stats, 0, 2 * dout * sizeof(float), stream);
      dim3 cgrid((dout + 255) / 256, 80);
      colstats_kernel<<<cgrid, 256, 0, stream>>>(S, dout, stats, 250);
      size_t total = (size_t)NNODES * dout;
      bn_relu_kernel<<<(total + 255) / 256, 256, 0, stream>>>(
          S, stats, ng[L], nb[L], dout, Hbf);
      lda = dout;
    }
  }
}

// Round 4
// 744.017 us; speedup vs baseline: 15.3033x; 1.1405x over previous
//
#include <hip/hip_runtime.h>
#include <math.h>

#define NNODES 20000
#define NEDGES 320000

typedef __bf16 bf16x8 __attribute__((ext_vector_type(8)));
typedef float f32x4 __attribute__((ext_vector_type(4)));
typedef unsigned short u16x4 __attribute__((ext_vector_type(4)));
typedef unsigned short u16x8 __attribute__((ext_vector_type(8)));

__device__ inline unsigned short f2bf(float x) {
  union { float f; unsigned int u; } q;
  q.f = x;
  unsigned int u = q.u;
  unsigned int r = (u + 0x7fffu + ((u >> 16) & 1u)) >> 16;
  return (unsigned short)r;
}

__device__ inline float bf2f(unsigned short u) {
  union { unsigned int u; float f; } q;
  q.u = ((unsigned int)u) << 16;
  return q.f;
}

// ---------------- embed: NeRF positional encoding -> bf16, stride 224, zero-pad ----
__global__ __launch_bounds__(256) void embed_kernel(const float* __restrict__ x,
                                                    unsigned short* __restrict__ h) {
  int n = blockIdx.x * blockDim.x + threadIdx.x;
  if (n >= NNODES) return;
  const float* xr = x + (size_t)n * 20;
  unsigned short* hr = h + (size_t)n * 224;
#pragma unroll
  for (int g = 0; g < 3; ++g) {
    float v0 = xr[g * 3 + 0], v1 = xr[g * 3 + 1], v2 = xr[g * 3 + 2];
    unsigned short* o = hr + g * 63;
    o[0] = f2bf(v0); o[1] = f2bf(v1); o[2] = f2bf(v2);
    float f = 1.0f;
    for (int fr = 0; fr < 10; ++fr) {
      float s0, c0, s1, c1, s2, c2;
      sincosf(v0 * f, &s0, &c0);
      sincosf(v1 * f, &s1, &c1);
      sincosf(v2 * f, &s2, &c2);
      int base = 3 + fr * 6;
      o[base + 0] = f2bf(s0); o[base + 1] = f2bf(s1); o[base + 2] = f2bf(s2);
      o[base + 3] = f2bf(c0); o[base + 4] = f2bf(c1); o[base + 5] = f2bf(c2);
      f *= 2.0f;
    }
  }
  for (int j = 0; j < 11; ++j) hr[189 + j] = f2bf(xr[9 + j]);
  for (int j = 200; j < 224; ++j) hr[j] = 0;
}

// ---------------- per-node in-degree counts ----------------
__global__ __launch_bounds__(256) void count_kernel(const int* __restrict__ edst,
                                                    int* __restrict__ cnt) {
  int e = blockIdx.x * blockDim.x + threadIdx.x;
  if (e < NEDGES) atomicAdd(&cnt[edst[e]], 1);
}

// ---------------- chunked exclusive scan (single block) ----------------
__global__ __launch_bounds__(256) void scan_kernel(const int* __restrict__ cnt,
                                                   int* __restrict__ rowptr,
                                                   int* __restrict__ head) {
  __shared__ int tsum[256];
  const int CH = (NNODES + 255) / 256;  // 79
  int t = threadIdx.x;
  int i0 = t * CH;
  int i1 = min(i0 + CH, NNODES);
  int s = 0;
  for (int i = i0; i < i1; ++i) s += cnt[i];
  tsum[t] = s;
  __syncthreads();
  for (int off = 1; off < 256; off <<= 1) {
    int v = (t >= off) ? tsum[t - off] : 0;
    __syncthreads();
    tsum[t] += v;
    __syncthreads();
  }
  int run = tsum[t] - s;
  for (int i = i0; i < i1; ++i) {
    rowptr[i] = run;
    head[i] = run;
    run += cnt[i];
  }
  if (t == 255) rowptr[NNODES] = run;
}

// ---------------- scatter edges into CSR buckets ----------------
__global__ __launch_bounds__(256) void scatter_kernel(const int* __restrict__ esrc,
                                                      const int* __restrict__ edst,
                                                      int* __restrict__ head,
                                                      int* __restrict__ csr_src) {
  int e = blockIdx.x * blockDim.x + threadIdx.x;
  if (e < NEDGES) {
    int pos = atomicAdd(&head[edst[e]], 1);
    csr_src[pos] = esrc[e];
  }
}

// ---------------- weight prep: Wt1[c][k] (bf16) ----------------
__global__ __launch_bounds__(256) void transpose_w1_kernel(
    const float* __restrict__ W1, int din, int dout, int Kpad,
    unsigned short* __restrict__ Wt1) {
  int idx = blockIdx.x * 256 + threadIdx.x;
  int total = 2 * dout * Kpad;
  if (idx >= total) return;
  int c = idx / Kpad, k = idx % Kpad;
  float v = 0.f;
  if (k < din)
    v = (c < dout) ? W1[(size_t)k * dout + c]
                   : W1[(size_t)(din + k) * dout + (c - dout)];
  Wt1[idx] = f2bf(v);
}

// ---------------- weight prep: Wt2[n][k] = W2[k][n] (bf16) ----------------
__global__ __launch_bounds__(256) void transpose_w2_kernel(
    const float* __restrict__ W2, int d, unsigned short* __restrict__ Wt2) {
  int idx = blockIdx.x * 256 + threadIdx.x;
  int total = d * d;
  if (idx >= total) return;
  int n = idx / d, k = idx % d;
  Wt2[idx] = f2bf(W2[(size_t)k * d + n]);
}

// ---------------- MFMA GEMM: C[M x Ncol] = A[M x K](bf16) @ Bt[Ncol x K]^T ----
// EPI 0: AVout (bf16) = acc + (col<dhalf ? bias[col] : 0)
// EPI 1: Cout (f32)   = cnt[row]>0 ? acc + bias[col] : 0
template <int EPI>
__global__ __launch_bounds__(256) void mfma_gemm_kernel(
    const unsigned short* __restrict__ A, int lda, int K,
    const unsigned short* __restrict__ Bt, int Ncol, int dhalf,
    const float* __restrict__ bias, const int* __restrict__ cnt,
    void* __restrict__ Cout) {
  __shared__ unsigned short sA[128 * 40];
  __shared__ unsigned short sB[64 * 40];
  int tid = threadIdx.x;
  int bR = blockIdx.y * 128, bC = blockIdx.x * 64;
  int wid = tid >> 6, lane = tid & 63;
  int wr = wid >> 1, wc = wid & 1;
  int lr = lane & 15, lg = lane >> 4;

  f32x4 acc[4][2];
#pragma unroll
  for (int fr = 0; fr < 4; ++fr)
#pragma unroll
    for (int fc = 0; fc < 2; ++fc) acc[fr][fc] = f32x4{0.f, 0.f, 0.f, 0.f};

  for (int k0 = 0; k0 < K; k0 += 32) {
#pragma unroll
    for (int rep = 0; rep < 2; ++rep) {
      int idx = tid + rep * 256;
      int row = idx >> 2, kq = (idx & 3) * 8;
      int gr = bR + row;
      bf16x8 v;
      if (gr < NNODES) {
        v = *(const bf16x8*)(A + (size_t)gr * lda + k0 + kq);
      } else {
#pragma unroll
        for (int i = 0; i < 8; ++i) v[i] = (__bf16)0.f;
      }
      *(bf16x8*)(sA + row * 40 + kq) = v;
    }
    {
      int n = tid >> 2, kq = (tid & 3) * 8;
      bf16x8 v = *(const bf16x8*)(Bt + (size_t)(bC + n) * K + k0 + kq);
      *(bf16x8*)(sB + n * 40 + kq) = v;
    }
    __syncthreads();
    bf16x8 aF[4], bF[2];
#pragma unroll
    for (int fr = 0; fr < 4; ++fr)
      aF[fr] = *(const bf16x8*)(sA + (wr * 64 + fr * 16 + lr) * 40 + lg * 8);
#pragma unroll
    for (int fc = 0; fc < 2; ++fc)
      bF[fc] = *(const bf16x8*)(sB + (wc * 32 + fc * 16 + lr) * 40 + lg * 8);
#pragma unroll
    for (int fr = 0; fr < 4; ++fr)
#pragma unroll
      for (int fc = 0; fc < 2; ++fc)
        acc[fr][fc] = __builtin_amdgcn_mfma_f32_16x16x32_bf16(
            aF[fr], bF[fc], acc[fr][fc], 0, 0, 0);
    __syncthreads();
  }

#pragma unroll
  for (int fr = 0; fr < 4; ++fr) {
#pragma unroll
    for (int j = 0; j < 4; ++j) {
      int gr = bR + wr * 64 + fr * 16 + lg * 4 + j;
      if (gr >= NNODES) continue;
      int ct = (EPI == 1) ? cnt[gr] : 1;
#pragma unroll
      for (int fc = 0; fc < 2; ++fc) {
        int gc = bC + wc * 32 + fc * 16 + lr;
        float v = acc[fr][fc][j];
        if (EPI == 0) {
          if (gc < dhalf) v += bias[gc];
          ((unsigned short*)Cout)[(size_t)gr * Ncol + gc] = f2bf(v);
        } else {
          v = (ct > 0) ? (v + bias[gc]) : 0.f;
          ((float*)Cout)[(size_t)gr * Ncol + gc] = v;
        }
      }
    }
  }
}

// ------- edge aggregation (gather, bf16): Y[n] = (1/cnt) * sum_e relu(A[n]-V[n]+V[src_e]) -------
template <int D>
__global__ __launch_bounds__(256) void edge_agg_kernel(
    const unsigned short* __restrict__ AV, const int* __restrict__ rowptr,
    const int* __restrict__ csr_src, unsigned short* __restrict__ Y) {
  constexpr int TPN = D / 8;        // threads per node (each owns 8 cols)
  constexpr int NPB = 256 / TPN;    // nodes per block
  int tid = threadIdx.x;
  int ln = tid % TPN;
  int sn = tid / TPN;
  int node = blockIdx.x * NPB + sn;
  if (node >= NNODES) return;
  int c = ln * 8;
  const unsigned short* Arow = AV + (size_t)node * 2 * D;
  u16x8 a8 = *(const u16x8*)(Arow + c);
  u16x8 v8 = *(const u16x8*)(Arow + D + c);
  float ad[8], acc[8];
#pragma unroll
  for (int i = 0; i < 8; ++i) {
    ad[i] = bf2f(a8[i]) - bf2f(v8[i]);
    acc[i] = 0.f;
  }
  int e0 = rowptr[node], e1 = rowptr[node + 1];
  int e = e0;
  for (; e + 3 < e1; e += 4) {
    int s0 = csr_src[e], s1 = csr_src[e + 1];
    int s2 = csr_src[e + 2], s3 = csr_src[e + 3];
    u16x8 w0 = *(const u16x8*)(AV + (size_t)s0 * 2 * D + D + c);
    u16x8 w1 = *(const u16x8*)(AV + (size_t)s1 * 2 * D + D + c);
    u16x8 w2 = *(const u16x8*)(AV + (size_t)s2 * 2 * D + D + c);
    u16x8 w3 = *(const u16x8*)(AV + (size_t)s3 * 2 * D + D + c);
#pragma unroll
    for (int i = 0; i < 8; ++i) {
      acc[i] += fmaxf(ad[i] + bf2f(w0[i]), 0.f) + fmaxf(ad[i] + bf2f(w1[i]), 0.f) +
                fmaxf(ad[i] + bf2f(w2[i]), 0.f) + fmaxf(ad[i] + bf2f(w3[i]), 0.f);
    }
  }
  for (; e < e1; ++e) {
    int s0 = csr_src[e];
    u16x8 w0 = *(const u16x8*)(AV + (size_t)s0 * 2 * D + D + c);
#pragma unroll
    for (int i = 0; i < 8; ++i) acc[i] += fmaxf(ad[i] + bf2f(w0[i]), 0.f);
  }
  float inv = (e1 > e0) ? 1.f / (float)(e1 - e0) : 0.f;
  u16x8 o;
#pragma unroll
  for (int i = 0; i < 8; ++i) o[i] = f2bf(acc[i] * inv);
  *(u16x8*)(Y + (size_t)node * D + c) = o;
}

// ---------------- column stats of S ----------------
__global__ __launch_bounds__(256) void colstats_kernel(
    const float* __restrict__ S, int dout, float* __restrict__ stats,
    int rows_per_block) {
  int c = blockIdx.x * blockDim.x + threadIdx.x;
  if (c >= dout) return;
  int r0 = blockIdx.y * rows_per_block;
  int r1 = min(r0 + rows_per_block, NNODES);
  float s = 0.f, s2 = 0.f;
  for (int r = r0; r < r1; ++r) {
    float y = S[(size_t)r * dout + c];
    s += y;
    s2 += y * y;
  }
  atomicAdd(&stats[c], s);
  atomicAdd(&stats[dout + c], s2);
}

// ---------------- BN(train) + ReLU -> H (bf16) ----------------
__global__ __launch_bounds__(256) void bn_relu_kernel(
    const float* __restrict__ S, const float* __restrict__ stats,
    const float* __restrict__ g, const float* __restrict__ bb, int dout,
    unsigned short* __restrict__ Hout) {
  size_t idx = (size_t)blockIdx.x * blockDim.x + threadIdx.x;
  size_t total = (size_t)NNODES * dout;
  if (idx >= total) return;
  int c = (int)(idx % dout);
  float mu = stats[c] * (1.0f / NNODES);
  float var = stats[dout + c] * (1.0f / NNODES) - mu * mu;
  float y = S[idx];
  float v = g[c] * (y - mu) * rsqrtf(var + 1e-5f) + bb[c];
  Hout[idx] = f2bf(fmaxf(v, 0.f));
}

static void launch_edge_agg(int dout, const unsigned short* AV, const int* rowptr,
                            const int* csr_src, unsigned short* Y,
                            hipStream_t st) {
  switch (dout) {
    case 64: {
      dim3 grid((NNODES + 31) / 32);
      hipLaunchKernelGGL((edge_agg_kernel<64>), grid, dim3(256), 0, st, AV, rowptr, csr_src, Y);
      break;
    }
    case 128: {
      dim3 grid((NNODES + 15) / 16);
      hipLaunchKernelGGL((edge_agg_kernel<128>), grid, dim3(256), 0, st, AV, rowptr, csr_src, Y);
      break;
    }
    case 256: {
      dim3 grid((NNODES + 7) / 8);
      hipLaunchKernelGGL((edge_agg_kernel<256>), grid, dim3(256), 0, st, AV, rowptr, csr_src, Y);
      break;
    }
    case 512: {
      dim3 grid((NNODES + 3) / 4);
      hipLaunchKernelGGL((edge_agg_kernel<512>), grid, dim3(256), 0, st, AV, rowptr, csr_src, Y);
      break;
    }
  }
}

extern "C" void kernel_launch(void* const* d_in, const int* in_sizes, int n_in,
                              void* d_out, int out_size, void* d_ws,
                              size_t ws_size, hipStream_t stream) {
  const float* x = (const float*)d_in[0];
  const int* edge_index = (const int*)d_in[1];
  const int* esrc = edge_index;            // edge_index[0]
  const int* edst = edge_index + NEDGES;   // edge_index[1]

  const float* gw1[5] = {(const float*)d_in[3],  (const float*)d_in[7],
                         (const float*)d_in[11], (const float*)d_in[15],
                         (const float*)d_in[19]};
  const float* gb1[5] = {(const float*)d_in[4],  (const float*)d_in[8],
                         (const float*)d_in[12], (const float*)d_in[16],
                         (const float*)d_in[20]};
  const float* gw2[5] = {(const float*)d_in[5],  (const float*)d_in[9],
                         (const float*)d_in[13], (const float*)d_in[17],
                         (const float*)d_in[21]};
  const float* gb2[5] = {(const float*)d_in[6],  (const float*)d_in[10],
                         (const float*)d_in[14], (const float*)d_in[18],
                         (const float*)d_in[22]};
  const float* ng[4] = {(const float*)d_in[23], (const float*)d_in[25],
                        (const float*)d_in[27], (const float*)d_in[29]};
  const float* nb[4] = {(const float*)d_in[24], (const float*)d_in[26],
                        (const float*)d_in[28], (const float*)d_in[30]};

  // workspace layout
  unsigned short* AV = (unsigned short*)d_ws;            // N x 1024 bf16
  float* S = (float*)(AV + (size_t)NNODES * 1024);       // N x 256 f32
  unsigned short* Hbf = (unsigned short*)(S + (size_t)NNODES * 256);  // N x 256 bf16 (L1: stride 224)
  unsigned short* Ybf = Hbf + (size_t)NNODES * 256;      // N x 512 bf16
  unsigned short* Wt1 = Ybf + (size_t)NNODES * 512;      // 1024*256 bf16
  unsigned short* Wt2 = Wt1 + 262144;                    // 512*512 bf16
  int* cnt = (int*)(Wt2 + 262144);                       // N
  int* rowptr = cnt + NNODES;                            // N+1
  int* head = rowptr + NNODES + 1;                       // N
  int* csr_src = head + NNODES;                          // E
  float* stats = (float*)(csr_src + NEDGES);             // 2 x 512

  const int dins[5] = {200, 64, 128, 256, 256};
  const int Kpads[5] = {224, 64, 128, 256, 256};
  const int douts[5] = {64, 128, 256, 256, 512};
  const int MBLK = (NNODES + 127) / 128;  // 157

  hipMemsetAsync(cnt, 0, NNODES * sizeof(int), stream);
  count_kernel<<<(NEDGES + 255) / 256, 256, 0, stream>>>(edst, cnt);
  scan_kernel<<<1, 256, 0, stream>>>(cnt, rowptr, head);
  scatter_kernel<<<(NEDGES + 255) / 256, 256, 0, stream>>>(esrc, edst, head, csr_src);
  embed_kernel<<<(NNODES + 255) / 256, 256, 0, stream>>>(x, Hbf);

  int lda = 224;
  for (int L = 0; L < 5; ++L) {
    int din = dins[L], Kp = Kpads[L], dout = douts[L];
    int tot1 = 2 * dout * Kp;
    transpose_w1_kernel<<<(tot1 + 255) / 256, 256, 0, stream>>>(gw1[L], din, dout, Kp, Wt1);
    // AV = [H@W1a + b1 | H@W1b] (bf16)
    dim3 g1(2 * dout / 64, MBLK);
    hipLaunchKernelGGL((mfma_gemm_kernel<0>), g1, dim3(256), 0, stream,
                       Hbf, lda, Kp, Wt1, 2 * dout, dout, gb1[L], (const int*)nullptr,
                       (void*)AV);
    // Y = scatter-mean of relu messages (gather over CSR) -> bf16
    launch_edge_agg(dout, AV, rowptr, csr_src, Ybf, stream);
    int tot2 = dout * dout;
    transpose_w2_kernel<<<(tot2 + 255) / 256, 256, 0, stream>>>(gw2[L], dout, Wt2);
    // S/out = Y @ W2 + b2 (cnt-masked)
    void* dst = (L < 4) ? (void*)S : (void*)d_out;
    dim3 g2(dout / 64, MBLK);
    hipLaunchKernelGGL((mfma_gemm_kernel<1>), g2, dim3(256), 0, stream,
                       Ybf, dout, dout, Wt2, dout, dout, gb2[L], cnt, dst);
    if (L < 4) {
      hipMemsetAsync(stats, 0, 2 * dout * sizeof(float), stream);
      dim3 cgrid((dout + 255) / 256, 80);
      colstats_kernel<<<cgrid, 256, 0, stream>>>(S, dout, stats, 250);
      size_t total = (size_t)NNODES * dout;
      bn_relu_kernel<<<(total + 255) / 256, 256, 0, stream>>>(
          S, stats, ng[L], nb[L], dout, Hbf);
      lda = dout;
    }
  }
}

// Round 5
// 552.795 us; speedup vs baseline: 20.5970x; 1.3459x over previous
//
#include <hip/hip_runtime.h>
#include <math.h>

#define NNODES 20000
#define NEDGES 320000

typedef __bf16 bf16x8 __attribute__((ext_vector_type(8)));
typedef float f32x4 __attribute__((ext_vector_type(4)));
typedef unsigned short u16x8 __attribute__((ext_vector_type(8)));

__device__ inline unsigned short f2bf(float x) {
  union { float f; unsigned int u; } q;
  q.f = x;
  unsigned int u = q.u;
  unsigned int r = (u + 0x7fffu + ((u >> 16) & 1u)) >> 16;
  return (unsigned short)r;
}

__device__ inline float bf2f(unsigned short u) {
  union { unsigned int u; float f; } q;
  q.u = ((unsigned int)u) << 16;
  return q.f;
}

// ---------------- embed: NeRF positional encoding -> bf16, stride 224, zero-pad ----
__global__ __launch_bounds__(256) void embed_kernel(const float* __restrict__ x,
                                                    unsigned short* __restrict__ h) {
  int n = blockIdx.x * blockDim.x + threadIdx.x;
  if (n >= NNODES) return;
  const float* xr = x + (size_t)n * 20;
  unsigned short* hr = h + (size_t)n * 224;
#pragma unroll
  for (int g = 0; g < 3; ++g) {
    float v0 = xr[g * 3 + 0], v1 = xr[g * 3 + 1], v2 = xr[g * 3 + 2];
    unsigned short* o = hr + g * 63;
    o[0] = f2bf(v0); o[1] = f2bf(v1); o[2] = f2bf(v2);
    float f = 1.0f;
    for (int fr = 0; fr < 10; ++fr) {
      float s0, c0, s1, c1, s2, c2;
      sincosf(v0 * f, &s0, &c0);
      sincosf(v1 * f, &s1, &c1);
      sincosf(v2 * f, &s2, &c2);
      int base = 3 + fr * 6;
      o[base + 0] = f2bf(s0); o[base + 1] = f2bf(s1); o[base + 2] = f2bf(s2);
      o[base + 3] = f2bf(c0); o[base + 4] = f2bf(c1); o[base + 5] = f2bf(c2);
      f *= 2.0f;
    }
  }
  for (int j = 0; j < 11; ++j) hr[189 + j] = f2bf(xr[9 + j]);
  for (int j = 200; j < 224; ++j) hr[j] = 0;
}

// ---------------- per-node in-degree counts ----------------
__global__ __launch_bounds__(256) void count_kernel(const int* __restrict__ edst,
                                                    int* __restrict__ cnt) {
  int e = blockIdx.x * blockDim.x + threadIdx.x;
  if (e < NEDGES) atomicAdd(&cnt[edst[e]], 1);
}

// ---------------- chunked exclusive scan (single block) ----------------
__global__ __launch_bounds__(256) void scan_kernel(const int* __restrict__ cnt,
                                                   int* __restrict__ rowptr,
                                                   int* __restrict__ head) {
  __shared__ int tsum[256];
  const int CH = (NNODES + 255) / 256;  // 79
  int t = threadIdx.x;
  int i0 = t * CH;
  int i1 = min(i0 + CH, NNODES);
  int s = 0;
  for (int i = i0; i < i1; ++i) s += cnt[i];
  tsum[t] = s;
  __syncthreads();
  for (int off = 1; off < 256; off <<= 1) {
    int v = (t >= off) ? tsum[t - off] : 0;
    __syncthreads();
    tsum[t] += v;
    __syncthreads();
  }
  int run = tsum[t] - s;
  for (int i = i0; i < i1; ++i) {
    rowptr[i] = run;
    head[i] = run;
    run += cnt[i];
  }
  if (t == 255) rowptr[NNODES] = run;
}

// ---------------- scatter edges into CSR buckets ----------------
__global__ __launch_bounds__(256) void scatter_kernel(const int* __restrict__ esrc,
                                                      const int* __restrict__ edst,
                                                      int* __restrict__ head,
                                                      int* __restrict__ csr_src) {
  int e = blockIdx.x * blockDim.x + threadIdx.x;
  if (e < NEDGES) {
    int pos = atomicAdd(&head[edst[e]], 1);
    csr_src[pos] = esrc[e];
  }
}

// ---------------- weight prep: Wt1[c][k] (bf16) ----------------
__global__ __launch_bounds__(256) void transpose_w1_kernel(
    const float* __restrict__ W1, int din, int dout, int Kpad,
    unsigned short* __restrict__ Wt1) {
  int idx = blockIdx.x * 256 + threadIdx.x;
  int total = 2 * dout * Kpad;
  if (idx >= total) return;
  int c = idx / Kpad, k = idx % Kpad;
  float v = 0.f;
  if (k < din)
    v = (c < dout) ? W1[(size_t)k * dout + c]
                   : W1[(size_t)(din + k) * dout + (c - dout)];
  Wt1[idx] = f2bf(v);
}

// ---------------- weight prep: Wt2[n][k] = W2[k][n] (bf16) ----------------
__global__ __launch_bounds__(256) void transpose_w2_kernel(
    const float* __restrict__ W2, int d, unsigned short* __restrict__ Wt2) {
  int idx = blockIdx.x * 256 + threadIdx.x;
  int total = d * d;
  if (idx >= total) return;
  int n = idx / d, k = idx % d;
  Wt2[idx] = f2bf(W2[(size_t)k * d + n]);
}

// ---------------- MFMA GEMM: C[M x Ncol] = A[M x K](bf16) @ Bt[Ncol x K]^T ----
// EPI 0: AVout (bf16) = acc + (col<dhalf ? bias[col] : 0)
// EPI 1: Cout (f32)   = cnt[row]>0 ? acc + bias[col] : 0
// EPI 2: EPI 1 + atomic column stats (sum, sumsq) into stats[]
template <int EPI>
__global__ __launch_bounds__(256) void mfma_gemm_kernel(
    const unsigned short* __restrict__ A, int lda, int K,
    const unsigned short* __restrict__ Bt, int Ncol, int dhalf,
    const float* __restrict__ bias, const int* __restrict__ cnt,
    float* __restrict__ stats, void* __restrict__ Cout) {
  __shared__ unsigned short sA[128 * 40];
  __shared__ unsigned short sB[64 * 40];
  int tid = threadIdx.x;
  int bR = blockIdx.y * 128, bC = blockIdx.x * 64;
  int wid = tid >> 6, lane = tid & 63;
  int wr = wid >> 1, wc = wid & 1;
  int lr = lane & 15, lg = lane >> 4;

  f32x4 acc[4][2];
#pragma unroll
  for (int fr = 0; fr < 4; ++fr)
#pragma unroll
    for (int fc = 0; fc < 2; ++fc) acc[fr][fc] = f32x4{0.f, 0.f, 0.f, 0.f};

  for (int k0 = 0; k0 < K; k0 += 32) {
#pragma unroll
    for (int rep = 0; rep < 2; ++rep) {
      int idx = tid + rep * 256;
      int row = idx >> 2, kq = (idx & 3) * 8;
      int gr = bR + row;
      bf16x8 v;
      if (gr < NNODES) {
        v = *(const bf16x8*)(A + (size_t)gr * lda + k0 + kq);
      } else {
#pragma unroll
        for (int i = 0; i < 8; ++i) v[i] = (__bf16)0.f;
      }
      *(bf16x8*)(sA + row * 40 + kq) = v;
    }
    {
      int n = tid >> 2, kq = (tid & 3) * 8;
      bf16x8 v = *(const bf16x8*)(Bt + (size_t)(bC + n) * K + k0 + kq);
      *(bf16x8*)(sB + n * 40 + kq) = v;
    }
    __syncthreads();
    bf16x8 aF[4], bF[2];
#pragma unroll
    for (int fr = 0; fr < 4; ++fr)
      aF[fr] = *(const bf16x8*)(sA + (wr * 64 + fr * 16 + lr) * 40 + lg * 8);
#pragma unroll
    for (int fc = 0; fc < 2; ++fc)
      bF[fc] = *(const bf16x8*)(sB + (wc * 32 + fc * 16 + lr) * 40 + lg * 8);
#pragma unroll
    for (int fr = 0; fr < 4; ++fr)
#pragma unroll
      for (int fc = 0; fc < 2; ++fc)
        acc[fr][fc] = __builtin_amdgcn_mfma_f32_16x16x32_bf16(
            aF[fr], bF[fc], acc[fr][fc], 0, 0, 0);
    __syncthreads();
  }

  float csum[2] = {0.f, 0.f}, csum2[2] = {0.f, 0.f};
#pragma unroll
  for (int fr = 0; fr < 4; ++fr) {
#pragma unroll
    for (int j = 0; j < 4; ++j) {
      int gr = bR + wr * 64 + fr * 16 + lg * 4 + j;
      if (gr >= NNODES) continue;
      int ct = (EPI >= 1) ? cnt[gr] : 1;
#pragma unroll
      for (int fc = 0; fc < 2; ++fc) {
        int gc = bC + wc * 32 + fc * 16 + lr;
        float v = acc[fr][fc][j];
        if (EPI == 0) {
          if (gc < dhalf) v += bias[gc];
          ((unsigned short*)Cout)[(size_t)gr * Ncol + gc] = f2bf(v);
        } else {
          v = (ct > 0) ? (v + bias[gc]) : 0.f;
          ((float*)Cout)[(size_t)gr * Ncol + gc] = v;
          if (EPI == 2) {
            csum[fc] += v;
            csum2[fc] += v * v;
          }
        }
      }
    }
  }
  if (EPI == 2) {
#pragma unroll
    for (int fc = 0; fc < 2; ++fc) {
      float s = csum[fc], s2 = csum2[fc];
      s += __shfl_xor(s, 16, 64);
      s += __shfl_xor(s, 32, 64);
      s2 += __shfl_xor(s2, 16, 64);
      s2 += __shfl_xor(s2, 32, 64);
      if (lg == 0) {
        int gc = bC + wc * 32 + fc * 16 + lr;
        atomicAdd(&stats[gc], s);
        atomicAdd(&stats[Ncol + gc], s2);
      }
    }
  }
}

// ------- edge aggregation (gather, bf16): Y[n] = (1/cnt) * sum_e relu(A[n]-V[n]+V[src_e]) -------
template <int D>
__global__ __launch_bounds__(256) void edge_agg_kernel(
    const unsigned short* __restrict__ AV, const int* __restrict__ rowptr,
    const int* __restrict__ csr_src, unsigned short* __restrict__ Y) {
  constexpr int TPN = D / 8;        // threads per node (each owns 8 cols)
  constexpr int NPB = 256 / TPN;    // nodes per block
  int tid = threadIdx.x;
  int ln = tid % TPN;
  int sn = tid / TPN;
  int node = blockIdx.x * NPB + sn;
  if (node >= NNODES) return;
  int c = ln * 8;
  const unsigned short* Arow = AV + (size_t)node * 2 * D;
  u16x8 a8 = *(const u16x8*)(Arow + c);
  u16x8 v8 = *(const u16x8*)(Arow + D + c);
  float ad[8], acc[8];
#pragma unroll
  for (int i = 0; i < 8; ++i) {
    ad[i] = bf2f(a8[i]) - bf2f(v8[i]);
    acc[i] = 0.f;
  }
  int e0 = rowptr[node], e1 = rowptr[node + 1];
  int e = e0;
  for (; e + 3 < e1; e += 4) {
    int s0 = csr_src[e], s1 = csr_src[e + 1];
    int s2 = csr_src[e + 2], s3 = csr_src[e + 3];
    u16x8 w0 = *(const u16x8*)(AV + (size_t)s0 * 2 * D + D + c);
    u16x8 w1 = *(const u16x8*)(AV + (size_t)s1 * 2 * D + D + c);
    u16x8 w2 = *(const u16x8*)(AV + (size_t)s2 * 2 * D + D + c);
    u16x8 w3 = *(const u16x8*)(AV + (size_t)s3 * 2 * D + D + c);
#pragma unroll
    for (int i = 0; i < 8; ++i) {
      acc[i] += fmaxf(ad[i] + bf2f(w0[i]), 0.f) + fmaxf(ad[i] + bf2f(w1[i]), 0.f) +
                fmaxf(ad[i] + bf2f(w2[i]), 0.f) + fmaxf(ad[i] + bf2f(w3[i]), 0.f);
    }
  }
  for (; e < e1; ++e) {
    int s0 = csr_src[e];
    u16x8 w0 = *(const u16x8*)(AV + (size_t)s0 * 2 * D + D + c);
#pragma unroll
    for (int i = 0; i < 8; ++i) acc[i] += fmaxf(ad[i] + bf2f(w0[i]), 0.f);
  }
  float inv = (e1 > e0) ? 1.f / (float)(e1 - e0) : 0.f;
  u16x8 o;
#pragma unroll
  for (int i = 0; i < 8; ++i) o[i] = f2bf(acc[i] * inv);
  *(u16x8*)(Y + (size_t)node * D + c) = o;
}

// ---------------- BN(train) + ReLU -> H (bf16) ----------------
__global__ __launch_bounds__(256) void bn_relu_kernel(
    const float* __restrict__ S, const float* __restrict__ stats,
    const float* __restrict__ g, const float* __restrict__ bb, int dout,
    unsigned short* __restrict__ Hout) {
  size_t idx = (size_t)blockIdx.x * blockDim.x + threadIdx.x;
  size_t total = (size_t)NNODES * dout;
  if (idx >= total) return;
  int c = (int)(idx % dout);
  float mu = stats[c] * (1.0f / NNODES);
  float var = stats[dout + c] * (1.0f / NNODES) - mu * mu;
  float y = S[idx];
  float v = g[c] * (y - mu) * rsqrtf(var + 1e-5f) + bb[c];
  Hout[idx] = f2bf(fmaxf(v, 0.f));
}

static void launch_edge_agg(int dout, const unsigned short* AV, const int* rowptr,
                            const int* csr_src, unsigned short* Y,
                            hipStream_t st) {
  switch (dout) {
    case 64: {
      dim3 grid((NNODES + 31) / 32);
      hipLaunchKernelGGL((edge_agg_kernel<64>), grid, dim3(256), 0, st, AV, rowptr, csr_src, Y);
      break;
    }
    case 128: {
      dim3 grid((NNODES + 15) / 16);
      hipLaunchKernelGGL((edge_agg_kernel<128>), grid, dim3(256), 0, st, AV, rowptr, csr_src, Y);
      break;
    }
    case 256: {
      dim3 grid((NNODES + 7) / 8);
      hipLaunchKernelGGL((edge_agg_kernel<256>), grid, dim3(256), 0, st, AV, rowptr, csr_src, Y);
      break;
    }
    case 512: {
      dim3 grid((NNODES + 3) / 4);
      hipLaunchKernelGGL((edge_agg_kernel<512>), grid, dim3(256), 0, st, AV, rowptr, csr_src, Y);
      break;
    }
  }
}

extern "C" void kernel_launch(void* const* d_in, const int* in_sizes, int n_in,
                              void* d_out, int out_size, void* d_ws,
                              size_t ws_size, hipStream_t stream) {
  const float* x = (const float*)d_in[0];
  const int* edge_index = (const int*)d_in[1];
  const int* esrc = edge_index;            // edge_index[0]
  const int* edst = edge_index + NEDGES;   // edge_index[1]

  const float* gw1[5] = {(const float*)d_in[3],  (const float*)d_in[7],
                         (const float*)d_in[11], (const float*)d_in[15],
                         (const float*)d_in[19]};
  const float* gb1[5] = {(const float*)d_in[4],  (const float*)d_in[8],
                         (const float*)d_in[12], (const float*)d_in[16],
                         (const float*)d_in[20]};
  const float* gw2[5] = {(const float*)d_in[5],  (const float*)d_in[9],
                         (const float*)d_in[13], (const float*)d_in[17],
                         (const float*)d_in[21]};
  const float* gb2[5] = {(const float*)d_in[6],  (const float*)d_in[10],
                         (const float*)d_in[14], (const float*)d_in[18],
                         (const float*)d_in[22]};
  const float* ng[4] = {(const float*)d_in[23], (const float*)d_in[25],
                        (const float*)d_in[27], (const float*)d_in[29]};
  const float* nb[4] = {(const float*)d_in[24], (const float*)d_in[26],
                        (const float*)d_in[28], (const float*)d_in[30]};

  // workspace layout
  unsigned short* AV = (unsigned short*)d_ws;            // N x 1024 bf16
  float* S = (float*)(AV + (size_t)NNODES * 1024);       // N x 256 f32
  unsigned short* Hbf = (unsigned short*)(S + (size_t)NNODES * 256);  // N x 256 bf16 (L1: stride 224)
  unsigned short* Ybf = Hbf + (size_t)NNODES * 256;      // N x 512 bf16
  unsigned short* Wt1 = Ybf + (size_t)NNODES * 512;      // 1024*256 bf16
  unsigned short* Wt2 = Wt1 + 262144;                    // 512*512 bf16
  int* cnt = (int*)(Wt2 + 262144);                       // N
  int* rowptr = cnt + NNODES;                            // N+1
  int* head = rowptr + NNODES + 1;                       // N
  int* csr_src = head + NNODES;                          // E
  float* stats = (float*)(csr_src + NEDGES);             // 2 x 512

  const int dins[5] = {200, 64, 128, 256, 256};
  const int Kpads[5] = {224, 64, 128, 256, 256};
  const int douts[5] = {64, 128, 256, 256, 512};
  const int MBLK = (NNODES + 127) / 128;  // 157

  hipMemsetAsync(cnt, 0, NNODES * sizeof(int), stream);
  count_kernel<<<(NEDGES + 255) / 256, 256, 0, stream>>>(edst, cnt);
  scan_kernel<<<1, 256, 0, stream>>>(cnt, rowptr, head);
  scatter_kernel<<<(NEDGES + 255) / 256, 256, 0, stream>>>(esrc, edst, head, csr_src);
  embed_kernel<<<(NNODES + 255) / 256, 256, 0, stream>>>(x, Hbf);

  int lda = 224;
  for (int L = 0; L < 5; ++L) {
    int din = dins[L], Kp = Kpads[L], dout = douts[L];
    int tot1 = 2 * dout * Kp;
    transpose_w1_kernel<<<(tot1 + 255) / 256, 256, 0, stream>>>(gw1[L], din, dout, Kp, Wt1);
    // AV = [H@W1a + b1 | H@W1b] (bf16)
    dim3 g1(2 * dout / 64, MBLK);
    hipLaunchKernelGGL((mfma_gemm_kernel<0>), g1, dim3(256), 0, stream,
                       Hbf, lda, Kp, Wt1, 2 * dout, dout, gb1[L], (const int*)nullptr,
                       (float*)nullptr, (void*)AV);
    // Y = scatter-mean of relu messages (gather over CSR) -> bf16
    launch_edge_agg(dout, AV, rowptr, csr_src, Ybf, stream);
    int tot2 = dout * dout;
    transpose_w2_kernel<<<(tot2 + 255) / 256, 256, 0, stream>>>(gw2[L], dout, Wt2);
    // S/out = Y @ W2 + b2 (cnt-masked), with fused column stats for layers 1-4
    dim3 g2(dout / 64, MBLK);
    if (L < 4) {
      hipMemsetAsync(stats, 0, 2 * dout * sizeof(float), stream);
      hipLaunchKernelGGL((mfma_gemm_kernel<2>), g2, dim3(256), 0, stream,
                         Ybf, dout, dout, Wt2, dout, dout, gb2[L], cnt, stats, (void*)S);
      size_t total = (size_t)NNODES * dout;
      bn_relu_kernel<<<(total + 255) / 256, 256, 0, stream>>>(
          S, stats, ng[L], nb[L], dout, Hbf);
      lda = dout;
    } else {
      hipLaunchKernelGGL((mfma_gemm_kernel<1>), g2, dim3(256), 0, stream,
                         Ybf, dout, dout, Wt2, dout, dout, gb2[L], cnt,
                         (float*)nullptr, (void*)d_out);
    }
  }
}

// Round 6
// 514.592 us; speedup vs baseline: 22.1261x; 1.0742x over previous
//
#include <hip/hip_runtime.h>
#include <math.h>

#define NNODES 20000
#define NEDGES 320000

typedef __bf16 bf16x8 __attribute__((ext_vector_type(8)));
typedef float f32x4 __attribute__((ext_vector_type(4)));
typedef unsigned short u16x8 __attribute__((ext_vector_type(8)));

__device__ inline unsigned short f2bf(float x) {
  union { float f; unsigned int u; } q;
  q.f = x;
  unsigned int u = q.u;
  unsigned int r = (u + 0x7fffu + ((u >> 16) & 1u)) >> 16;
  return (unsigned short)r;
}

__device__ inline float bf2f(unsigned short u) {
  union { unsigned int u; float f; } q;
  q.u = ((unsigned int)u) << 16;
  return q.f;
}

// ---------------- embed: NeRF positional encoding -> bf16, stride 224, zero-pad ----
__global__ __launch_bounds__(256) void embed_kernel(const float* __restrict__ x,
                                                    unsigned short* __restrict__ h) {
  int n = blockIdx.x * blockDim.x + threadIdx.x;
  if (n >= NNODES) return;
  const float* xr = x + (size_t)n * 20;
  unsigned short* hr = h + (size_t)n * 224;
#pragma unroll
  for (int g = 0; g < 3; ++g) {
    float v0 = xr[g * 3 + 0], v1 = xr[g * 3 + 1], v2 = xr[g * 3 + 2];
    unsigned short* o = hr + g * 63;
    o[0] = f2bf(v0); o[1] = f2bf(v1); o[2] = f2bf(v2);
    float f = 1.0f;
    for (int fr = 0; fr < 10; ++fr) {
      float s0, c0, s1, c1, s2, c2;
      sincosf(v0 * f, &s0, &c0);
      sincosf(v1 * f, &s1, &c1);
      sincosf(v2 * f, &s2, &c2);
      int base = 3 + fr * 6;
      o[base + 0] = f2bf(s0); o[base + 1] = f2bf(s1); o[base + 2] = f2bf(s2);
      o[base + 3] = f2bf(c0); o[base + 4] = f2bf(c1); o[base + 5] = f2bf(c2);
      f *= 2.0f;
    }
  }
  for (int j = 0; j < 11; ++j) hr[189 + j] = f2bf(xr[9 + j]);
  for (int j = 200; j < 224; ++j) hr[j] = 0;
}

// ---------------- per-node in-degree counts ----------------
__global__ __launch_bounds__(256) void count_kernel(const int* __restrict__ edst,
                                                    int* __restrict__ cnt) {
  int e = blockIdx.x * blockDim.x + threadIdx.x;
  if (e < NEDGES) atomicAdd(&cnt[edst[e]], 1);
}

// ---------------- chunked exclusive scan (single block) ----------------
__global__ __launch_bounds__(256) void scan_kernel(const int* __restrict__ cnt,
                                                   int* __restrict__ rowptr,
                                                   int* __restrict__ head) {
  __shared__ int tsum[256];
  const int CH = (NNODES + 255) / 256;  // 79
  int t = threadIdx.x;
  int i0 = t * CH;
  int i1 = min(i0 + CH, NNODES);
  int s = 0;
  for (int i = i0; i < i1; ++i) s += cnt[i];
  tsum[t] = s;
  __syncthreads();
  for (int off = 1; off < 256; off <<= 1) {
    int v = (t >= off) ? tsum[t - off] : 0;
    __syncthreads();
    tsum[t] += v;
    __syncthreads();
  }
  int run = tsum[t] - s;
  for (int i = i0; i < i1; ++i) {
    rowptr[i] = run;
    head[i] = run;
    run += cnt[i];
  }
  if (t == 255) rowptr[NNODES] = run;
}

// ---------------- scatter edges into CSR buckets ----------------
__global__ __launch_bounds__(256) void scatter_kernel(const int* __restrict__ esrc,
                                                      const int* __restrict__ edst,
                                                      int* __restrict__ head,
                                                      int* __restrict__ csr_src) {
  int e = blockIdx.x * blockDim.x + threadIdx.x;
  if (e < NEDGES) {
    int pos = atomicAdd(&head[edst[e]], 1);
    csr_src[pos] = esrc[e];
  }
}

// ---------------- combined weight prep (all layers, one launch) ----------------
struct WPtrs {
  const float* w1[5];
  const float* w2[5];
};

// Wt1 layer element counts: 2*dout*Kpad; offsets cumulative.
#define WT1_TOTAL 503808
#define WT2_TOTAL 413696

__global__ __launch_bounds__(256) void weight_prep_kernel(
    WPtrs p, unsigned short* __restrict__ Wt1All,
    unsigned short* __restrict__ Wt2All) {
  int idx = blockIdx.x * 256 + threadIdx.x;
  if (idx < WT1_TOTAL) {
    int L, off, din, dout, Kpad;
    if (idx < 28672)       { L = 0; off = 0;      din = 200; dout = 64;  Kpad = 224; }
    else if (idx < 45056)  { L = 1; off = 28672;  din = 64;  dout = 128; Kpad = 64;  }
    else if (idx < 110592) { L = 2; off = 45056;  din = 128; dout = 256; Kpad = 128; }
    else if (idx < 241664) { L = 3; off = 110592; din = 256; dout = 256; Kpad = 256; }
    else                   { L = 4; off = 241664; din = 256; dout = 512; Kpad = 256; }
    int local = idx - off;
    int c = local / Kpad, k = local % Kpad;
    float v = 0.f;
    if (k < din)
      v = (c < dout) ? p.w1[L][(size_t)k * dout + c]
                     : p.w1[L][(size_t)(din + k) * dout + (c - dout)];
    Wt1All[idx] = f2bf(v);
    return;
  }
  int jdx = idx - WT1_TOTAL;
  if (jdx >= WT2_TOTAL) return;
  int L, off, d;
  if (jdx < 4096)        { L = 0; off = 0;      d = 64;  }
  else if (jdx < 20480)  { L = 1; off = 4096;   d = 128; }
  else if (jdx < 86016)  { L = 2; off = 20480;  d = 256; }
  else if (jdx < 151552) { L = 3; off = 86016;  d = 256; }
  else                   { L = 4; off = 151552; d = 512; }
  int local = jdx - off;
  int n = local / d, k = local % d;
  Wt2All[jdx] = f2bf(p.w2[L][(size_t)k * d + n]);
}

// ---------------- MFMA GEMM: C[M x Ncol] = A[M x K](bf16) @ Bt[Ncol x K]^T ----
// EPI 0: AVout (bf16) = acc + (col<dhalf ? bias[col] : 0)
// EPI 1: Cout (f32)   = cnt[row]>0 ? acc + bias[col] : 0
// EPI 2: EPI 1 + atomic column stats (sum, sumsq) into stats[]
template <int EPI>
__global__ __launch_bounds__(256) void mfma_gemm_kernel(
    const unsigned short* __restrict__ A, int lda, int K,
    const unsigned short* __restrict__ Bt, int Ncol, int dhalf,
    const float* __restrict__ bias, const int* __restrict__ cnt,
    float* __restrict__ stats, void* __restrict__ Cout) {
  __shared__ unsigned short sA[128 * 40];
  __shared__ unsigned short sB[64 * 40];
  int tid = threadIdx.x;
  int bR = blockIdx.y * 128, bC = blockIdx.x * 64;
  int wid = tid >> 6, lane = tid & 63;
  int wr = wid >> 1, wc = wid & 1;
  int lr = lane & 15, lg = lane >> 4;

  f32x4 acc[4][2];
#pragma unroll
  for (int fr = 0; fr < 4; ++fr)
#pragma unroll
    for (int fc = 0; fc < 2; ++fc) acc[fr][fc] = f32x4{0.f, 0.f, 0.f, 0.f};

  for (int k0 = 0; k0 < K; k0 += 32) {
#pragma unroll
    for (int rep = 0; rep < 2; ++rep) {
      int idx = tid + rep * 256;
      int row = idx >> 2, kq = (idx & 3) * 8;
      int gr = bR + row;
      bf16x8 v;
      if (gr < NNODES) {
        v = *(const bf16x8*)(A + (size_t)gr * lda + k0 + kq);
      } else {
#pragma unroll
        for (int i = 0; i < 8; ++i) v[i] = (__bf16)0.f;
      }
      *(bf16x8*)(sA + row * 40 + kq) = v;
    }
    {
      int n = tid >> 2, kq = (tid & 3) * 8;
      bf16x8 v = *(const bf16x8*)(Bt + (size_t)(bC + n) * K + k0 + kq);
      *(bf16x8*)(sB + n * 40 + kq) = v;
    }
    __syncthreads();
    bf16x8 aF[4], bF[2];
#pragma unroll
    for (int fr = 0; fr < 4; ++fr)
      aF[fr] = *(const bf16x8*)(sA + (wr * 64 + fr * 16 + lr) * 40 + lg * 8);
#pragma unroll
    for (int fc = 0; fc < 2; ++fc)
      bF[fc] = *(const bf16x8*)(sB + (wc * 32 + fc * 16 + lr) * 40 + lg * 8);
#pragma unroll
    for (int fr = 0; fr < 4; ++fr)
#pragma unroll
      for (int fc = 0; fc < 2; ++fc)
        acc[fr][fc] = __builtin_amdgcn_mfma_f32_16x16x32_bf16(
            aF[fr], bF[fc], acc[fr][fc], 0, 0, 0);
    __syncthreads();
  }

  float csum[2] = {0.f, 0.f}, csum2[2] = {0.f, 0.f};
#pragma unroll
  for (int fr = 0; fr < 4; ++fr) {
#pragma unroll
    for (int j = 0; j < 4; ++j) {
      int gr = bR + wr * 64 + fr * 16 + lg * 4 + j;
      if (gr >= NNODES) continue;
      int ct = (EPI >= 1) ? cnt[gr] : 1;
#pragma unroll
      for (int fc = 0; fc < 2; ++fc) {
        int gc = bC + wc * 32 + fc * 16 + lr;
        float v = acc[fr][fc][j];
        if (EPI == 0) {
          if (gc < dhalf) v += bias[gc];
          ((unsigned short*)Cout)[(size_t)gr * Ncol + gc] = f2bf(v);
        } else {
          v = (ct > 0) ? (v + bias[gc]) : 0.f;
          ((float*)Cout)[(size_t)gr * Ncol + gc] = v;
          if (EPI == 2) {
            csum[fc] += v;
            csum2[fc] += v * v;
          }
        }
      }
    }
  }
  if (EPI == 2) {
#pragma unroll
    for (int fc = 0; fc < 2; ++fc) {
      float s = csum[fc], s2 = csum2[fc];
      s += __shfl_xor(s, 16, 64);
      s += __shfl_xor(s, 32, 64);
      s2 += __shfl_xor(s2, 16, 64);
      s2 += __shfl_xor(s2, 32, 64);
      if (lg == 0) {
        int gc = bC + wc * 32 + fc * 16 + lr;
        atomicAdd(&stats[gc], s);
        atomicAdd(&stats[Ncol + gc], s2);
      }
    }
  }
}

// ------- edge aggregation (gather, bf16, XCD column-sliced) -------
// Y[n, slice] = (1/cnt) * sum_e relu(A[n]-V[n]+V[src_e]) over a 64-col slice.
// slice = blockIdx.x % SLICES: consecutive blocks round-robin across the 8
// XCDs, so each XCD sees one slice; slice working set (20000*64*2B = 2.56 MB)
// stays resident in its 4 MB L2 -> no cross-XCD HBM refetch.
template <int D, int SLICES>
__global__ __launch_bounds__(256) void edge_agg_kernel(
    const unsigned short* __restrict__ AV, const int* __restrict__ rowptr,
    const int* __restrict__ csr_src, unsigned short* __restrict__ Y) {
  int slice = blockIdx.x % SLICES;
  int ngrp = blockIdx.x / SLICES;
  int tid = threadIdx.x;
  int ln = tid & 7;   // 8 threads per node, 8 cols each
  int sn = tid >> 3;  // 32 nodes per block
  int node = ngrp * 32 + sn;
  if (node >= NNODES) return;
  int c = slice * 64 + ln * 8;
  const unsigned short* Arow = AV + (size_t)node * 2 * D;
  u16x8 a8 = *(const u16x8*)(Arow + c);
  u16x8 v8 = *(const u16x8*)(Arow + D + c);
  float ad[8], acc[8];
#pragma unroll
  for (int i = 0; i < 8; ++i) {
    ad[i] = bf2f(a8[i]) - bf2f(v8[i]);
    acc[i] = 0.f;
  }
  int e0 = rowptr[node], e1 = rowptr[node + 1];
  int e = e0;
  for (; e + 3 < e1; e += 4) {
    int s0 = csr_src[e], s1 = csr_src[e + 1];
    int s2 = csr_src[e + 2], s3 = csr_src[e + 3];
    u16x8 w0 = *(const u16x8*)(AV + (size_t)s0 * 2 * D + D + c);
    u16x8 w1 = *(const u16x8*)(AV + (size_t)s1 * 2 * D + D + c);
    u16x8 w2 = *(const u16x8*)(AV + (size_t)s2 * 2 * D + D + c);
    u16x8 w3 = *(const u16x8*)(AV + (size_t)s3 * 2 * D + D + c);
#pragma unroll
    for (int i = 0; i < 8; ++i) {
      acc[i] += fmaxf(ad[i] + bf2f(w0[i]), 0.f) + fmaxf(ad[i] + bf2f(w1[i]), 0.f) +
                fmaxf(ad[i] + bf2f(w2[i]), 0.f) + fmaxf(ad[i] + bf2f(w3[i]), 0.f);
    }
  }
  for (; e < e1; ++e) {
    int s0 = csr_src[e];
    u16x8 w0 = *(const u16x8*)(AV + (size_t)s0 * 2 * D + D + c);
#pragma unroll
    for (int i = 0; i < 8; ++i) acc[i] += fmaxf(ad[i] + bf2f(w0[i]), 0.f);
  }
  float inv = (e1 > e0) ? 1.f / (float)(e1 - e0) : 0.f;
  u16x8 o;
#pragma unroll
  for (int i = 0; i < 8; ++i) o[i] = f2bf(acc[i] * inv);
  *(u16x8*)(Y + (size_t)node * D + c) = o;
}

// ---------------- BN(train) + ReLU -> H (bf16) ----------------
__global__ __launch_bounds__(256) void bn_relu_kernel(
    const float* __restrict__ S, const float* __restrict__ stats,
    const float* __restrict__ g, const float* __restrict__ bb, int dout,
    unsigned short* __restrict__ Hout) {
  size_t idx = (size_t)blockIdx.x * blockDim.x + threadIdx.x;
  size_t total = (size_t)NNODES * dout;
  if (idx >= total) return;
  int c = (int)(idx % dout);
  float mu = stats[c] * (1.0f / NNODES);
  float var = stats[dout + c] * (1.0f / NNODES) - mu * mu;
  float y = S[idx];
  float v = g[c] * (y - mu) * rsqrtf(var + 1e-5f) + bb[c];
  Hout[idx] = f2bf(fmaxf(v, 0.f));
}

static void launch_edge_agg(int dout, const unsigned short* AV, const int* rowptr,
                            const int* csr_src, unsigned short* Y,
                            hipStream_t st) {
  const int NG = (NNODES + 31) / 32;  // 625 node groups
  switch (dout) {
    case 64:
      hipLaunchKernelGGL((edge_agg_kernel<64, 1>), dim3(NG * 1), dim3(256), 0, st,
                         AV, rowptr, csr_src, Y);
      break;
    case 128:
      hipLaunchKernelGGL((edge_agg_kernel<128, 2>), dim3(NG * 2), dim3(256), 0, st,
                         AV, rowptr, csr_src, Y);
      break;
    case 256:
      hipLaunchKernelGGL((edge_agg_kernel<256, 4>), dim3(NG * 4), dim3(256), 0, st,
                         AV, rowptr, csr_src, Y);
      break;
    case 512:
      hipLaunchKernelGGL((edge_agg_kernel<512, 8>), dim3(NG * 8), dim3(256), 0, st,
                         AV, rowptr, csr_src, Y);
      break;
  }
}

extern "C" void kernel_launch(void* const* d_in, const int* in_sizes, int n_in,
                              void* d_out, int out_size, void* d_ws,
                              size_t ws_size, hipStream_t stream) {
  const float* x = (const float*)d_in[0];
  const int* edge_index = (const int*)d_in[1];
  const int* esrc = edge_index;            // edge_index[0]
  const int* edst = edge_index + NEDGES;   // edge_index[1]

  const float* gw1[5] = {(const float*)d_in[3],  (const float*)d_in[7],
                         (const float*)d_in[11], (const float*)d_in[15],
                         (const float*)d_in[19]};
  const float* gb1[5] = {(const float*)d_in[4],  (const float*)d_in[8],
                         (const float*)d_in[12], (const float*)d_in[16],
                         (const float*)d_in[20]};
  const float* gw2[5] = {(const float*)d_in[5],  (const float*)d_in[9],
                         (const float*)d_in[13], (const float*)d_in[17],
                         (const float*)d_in[21]};
  const float* gb2[5] = {(const float*)d_in[6],  (const float*)d_in[10],
                         (const float*)d_in[14], (const float*)d_in[18],
                         (const float*)d_in[22]};
  const float* ng[4] = {(const float*)d_in[23], (const float*)d_in[25],
                        (const float*)d_in[27], (const float*)d_in[29]};
  const float* nb[4] = {(const float*)d_in[24], (const float*)d_in[26],
                        (const float*)d_in[28], (const float*)d_in[30]};

  // workspace layout
  unsigned short* AV = (unsigned short*)d_ws;            // N x 1024 bf16
  float* S = (float*)(AV + (size_t)NNODES * 1024);       // N x 256 f32
  unsigned short* Hbf = (unsigned short*)(S + (size_t)NNODES * 256);  // N x 256 bf16 (L1: stride 224)
  unsigned short* Ybf = Hbf + (size_t)NNODES * 256;      // N x 512 bf16
  unsigned short* Wt1All = Ybf + (size_t)NNODES * 512;   // 503808 bf16
  unsigned short* Wt2All = Wt1All + WT1_TOTAL;           // 413696 bf16
  int* cnt = (int*)(Wt2All + WT2_TOTAL);                 // N
  int* rowptr = cnt + NNODES;                            // N+1
  int* head = rowptr + NNODES + 1;                       // N
  int* csr_src = head + NNODES;                          // E
  float* stats = (float*)(csr_src + NEDGES);             // 2 x 512

  const int Kpads[5] = {224, 64, 128, 256, 256};
  const int douts[5] = {64, 128, 256, 256, 512};
  const int wt1_off[5] = {0, 28672, 45056, 110592, 241664};
  const int wt2_off[5] = {0, 4096, 20480, 86016, 151552};
  const int MBLK = (NNODES + 127) / 128;  // 157

  hipMemsetAsync(cnt, 0, NNODES * sizeof(int), stream);
  count_kernel<<<(NEDGES + 255) / 256, 256, 0, stream>>>(edst, cnt);
  scan_kernel<<<1, 256, 0, stream>>>(cnt, rowptr, head);
  scatter_kernel<<<(NEDGES + 255) / 256, 256, 0, stream>>>(esrc, edst, head, csr_src);
  embed_kernel<<<(NNODES + 255) / 256, 256, 0, stream>>>(x, Hbf);

  WPtrs wp;
  for (int i = 0; i < 5; ++i) { wp.w1[i] = gw1[i]; wp.w2[i] = gw2[i]; }
  weight_prep_kernel<<<(WT1_TOTAL + WT2_TOTAL + 255) / 256, 256, 0, stream>>>(
      wp, Wt1All, Wt2All);

  int lda = 224;
  for (int L = 0; L < 5; ++L) {
    int Kp = Kpads[L], dout = douts[L];
    // AV = [H@W1a + b1 | H@W1b] (bf16)
    dim3 g1(2 * dout / 64, MBLK);
    hipLaunchKernelGGL((mfma_gemm_kernel<0>), g1, dim3(256), 0, stream,
                       Hbf, lda, Kp, Wt1All + wt1_off[L], 2 * dout, dout, gb1[L],
                       (const int*)nullptr, (float*)nullptr, (void*)AV);
    // Y = scatter-mean of relu messages (gather over CSR, XCD-sliced) -> bf16
    launch_edge_agg(dout, AV, rowptr, csr_src, Ybf, stream);
    // S/out = Y @ W2 + b2 (cnt-masked), with fused column stats for layers 1-4
    dim3 g2(dout / 64, MBLK);
    if (L < 4) {
      hipMemsetAsync(stats, 0, 2 * dout * sizeof(float), stream);
      hipLaunchKernelGGL((mfma_gemm_kernel<2>), g2, dim3(256), 0, stream,
                         Ybf, dout, dout, Wt2All + wt2_off[L], dout, dout, gb2[L],
                         cnt, stats, (void*)S);
      size_t total = (size_t)NNODES * dout;
      bn_relu_kernel<<<(total + 255) / 256, 256, 0, stream>>>(
          S, stats, ng[L], nb[L], dout, Hbf);
      lda = dout;
    } else {
      hipLaunchKernelGGL((mfma_gemm_kernel<1>), g2, dim3(256), 0, stream,
                         Ybf, dout, dout, Wt2All + wt2_off[L], dout, dout, gb2[L],
                         cnt, (float*)nullptr, (void*)d_out);
    }
  }
}

// Round 7
// 461.667 us; speedup vs baseline: 24.6627x; 1.1146x over previous
//
#include <hip/hip_runtime.h>
#include <math.h>

#define NNODES 20000
#define NEDGES 320000
#define NB 79  // ceil(NNODES/256)

typedef __bf16 bf16x8 __attribute__((ext_vector_type(8)));
typedef float f32x4 __attribute__((ext_vector_type(4)));
typedef unsigned short u16x8 __attribute__((ext_vector_type(8)));

__device__ inline unsigned short f2bf(float x) {
  union { float f; unsigned int u; } q;
  q.f = x;
  unsigned int u = q.u;
  unsigned int r = (u + 0x7fffu + ((u >> 16) & 1u)) >> 16;
  return (unsigned short)r;
}

__device__ inline float bf2f(unsigned short u) {
  union { unsigned int u; float f; } q;
  q.u = ((unsigned int)u) << 16;
  return q.f;
}

// ---------------- embed: NeRF positional encoding -> bf16, stride 224, zero-pad ----
__global__ __launch_bounds__(256) void embed_kernel(const float* __restrict__ x,
                                                    unsigned short* __restrict__ h) {
  int n = blockIdx.x * blockDim.x + threadIdx.x;
  if (n >= NNODES) return;
  const float* xr = x + (size_t)n * 20;
  unsigned short* hr = h + (size_t)n * 224;
#pragma unroll
  for (int g = 0; g < 3; ++g) {
    float v0 = xr[g * 3 + 0], v1 = xr[g * 3 + 1], v2 = xr[g * 3 + 2];
    unsigned short* o = hr + g * 63;
    o[0] = f2bf(v0); o[1] = f2bf(v1); o[2] = f2bf(v2);
    float f = 1.0f;
    for (int fr = 0; fr < 10; ++fr) {
      float s0, c0, s1, c1, s2, c2;
      sincosf(v0 * f, &s0, &c0);
      sincosf(v1 * f, &s1, &c1);
      sincosf(v2 * f, &s2, &c2);
      int base = 3 + fr * 6;
      o[base + 0] = f2bf(s0); o[base + 1] = f2bf(s1); o[base + 2] = f2bf(s2);
      o[base + 3] = f2bf(c0); o[base + 4] = f2bf(c1); o[base + 5] = f2bf(c2);
      f *= 2.0f;
    }
  }
  for (int j = 0; j < 11; ++j) hr[189 + j] = f2bf(xr[9 + j]);
  for (int j = 200; j < 224; ++j) hr[j] = 0;
}

// ---------------- per-node in-degree counts ----------------
__global__ __launch_bounds__(256) void count_kernel(const int* __restrict__ edst,
                                                    int* __restrict__ cnt) {
  int e = blockIdx.x * blockDim.x + threadIdx.x;
  if (e < NEDGES) atomicAdd(&cnt[edst[e]], 1);
}

// ---------------- parallel scan: pass1 per-block sums ----------------
__global__ __launch_bounds__(256) void scan_pass1(const int* __restrict__ cnt,
                                                  int* __restrict__ bsum) {
  __shared__ int red[256];
  int i = blockIdx.x * 256 + threadIdx.x;
  int v = (i < NNODES) ? cnt[i] : 0;
  red[threadIdx.x] = v;
  __syncthreads();
#pragma unroll
  for (int off = 128; off > 0; off >>= 1) {
    if (threadIdx.x < off) red[threadIdx.x] += red[threadIdx.x + off];
    __syncthreads();
  }
  if (threadIdx.x == 0) bsum[blockIdx.x] = red[0];
}

// ---------------- parallel scan: pass2 scan the NB block sums ----------------
__global__ __launch_bounds__(128) void scan_pass2(const int* __restrict__ bsum,
                                                  int* __restrict__ boff) {
  __shared__ int buf[128];
  int t = threadIdx.x;
  int v = (t < NB) ? bsum[t] : 0;
  buf[t] = v;
  __syncthreads();
#pragma unroll
  for (int off = 1; off < 128; off <<= 1) {
    int u = (t >= off) ? buf[t - off] : 0;
    __syncthreads();
    buf[t] += u;
    __syncthreads();
  }
  if (t < NB) boff[t] = buf[t] - v;  // exclusive
}

// ---------------- parallel scan: pass3 local scan + offset -> rowptr/head ----
__global__ __launch_bounds__(256) void scan_pass3(const int* __restrict__ cnt,
                                                  const int* __restrict__ boff,
                                                  int* __restrict__ rowptr,
                                                  int* __restrict__ head) {
  __shared__ int buf[256];
  int i = blockIdx.x * 256 + threadIdx.x;
  int v = (i < NNODES) ? cnt[i] : 0;
  buf[threadIdx.x] = v;
  __syncthreads();
#pragma unroll
  for (int off = 1; off < 256; off <<= 1) {
    int u = (threadIdx.x >= off) ? buf[threadIdx.x - off] : 0;
    __syncthreads();
    buf[threadIdx.x] += u;
    __syncthreads();
  }
  if (i < NNODES) {
    int excl = boff[blockIdx.x] + buf[threadIdx.x] - v;
    rowptr[i] = excl;
    head[i] = excl;
  }
  if (i == 0) rowptr[NNODES] = NEDGES;  // every edge has a valid dst
}

// ---------------- scatter edges into CSR buckets ----------------
__global__ __launch_bounds__(256) void scatter_kernel(const int* __restrict__ esrc,
                                                      const int* __restrict__ edst,
                                                      int* __restrict__ head,
                                                      int* __restrict__ csr_src) {
  int e = blockIdx.x * blockDim.x + threadIdx.x;
  if (e < NEDGES) {
    int pos = atomicAdd(&head[edst[e]], 1);
    csr_src[pos] = esrc[e];
  }
}

// ---------------- combined weight prep (all layers, one launch) ----------------
struct WPtrs {
  const float* w1[5];
  const float* w2[5];
};

#define WT1_TOTAL 503808
#define WT2_TOTAL 413696

__global__ __launch_bounds__(256) void weight_prep_kernel(
    WPtrs p, unsigned short* __restrict__ Wt1All,
    unsigned short* __restrict__ Wt2All) {
  int idx = blockIdx.x * 256 + threadIdx.x;
  if (idx < WT1_TOTAL) {
    int L, off, din, dout, Kpad;
    if (idx < 28672)       { L = 0; off = 0;      din = 200; dout = 64;  Kpad = 224; }
    else if (idx < 45056)  { L = 1; off = 28672;  din = 64;  dout = 128; Kpad = 64;  }
    else if (idx < 110592) { L = 2; off = 45056;  din = 128; dout = 256; Kpad = 128; }
    else if (idx < 241664) { L = 3; off = 110592; din = 256; dout = 256; Kpad = 256; }
    else                   { L = 4; off = 241664; din = 256; dout = 512; Kpad = 256; }
    int local = idx - off;
    int c = local / Kpad, k = local % Kpad;
    float v = 0.f;
    if (k < din)
      v = (c < dout) ? p.w1[L][(size_t)k * dout + c]
                     : p.w1[L][(size_t)(din + k) * dout + (c - dout)];
    Wt1All[idx] = f2bf(v);
    return;
  }
  int jdx = idx - WT1_TOTAL;
  if (jdx >= WT2_TOTAL) return;
  int L, off, d;
  if (jdx < 4096)        { L = 0; off = 0;      d = 64;  }
  else if (jdx < 20480)  { L = 1; off = 4096;   d = 128; }
  else if (jdx < 86016)  { L = 2; off = 20480;  d = 256; }
  else if (jdx < 151552) { L = 3; off = 86016;  d = 256; }
  else                   { L = 4; off = 151552; d = 512; }
  int local = jdx - off;
  int n = local / d, k = local % d;
  Wt2All[jdx] = f2bf(p.w2[L][(size_t)k * d + n]);
}

// ---------------- MFMA GEMM: C[M x Ncol] = A[M x K](bf16) @ Bt[Ncol x K]^T ----
// EPI 0: AVout (bf16) = acc + (col<dhalf ? bias[col] : 0)
// EPI 1: Cout (f32)   = cnt[row]>0 ? acc + bias[col] : 0
// EPI 2: EPI 1 + atomic column stats (sum, sumsq) into stats[]
template <int EPI>
__global__ __launch_bounds__(256) void mfma_gemm_kernel(
    const unsigned short* __restrict__ A, int lda, int K,
    const unsigned short* __restrict__ Bt, int Ncol, int dhalf,
    const float* __restrict__ bias, const int* __restrict__ cnt,
    float* __restrict__ stats, void* __restrict__ Cout) {
  __shared__ unsigned short sA[128 * 40];
  __shared__ unsigned short sB[64 * 40];
  int tid = threadIdx.x;
  int bR = blockIdx.y * 128, bC = blockIdx.x * 64;
  int wid = tid >> 6, lane = tid & 63;
  int wr = wid >> 1, wc = wid & 1;
  int lr = lane & 15, lg = lane >> 4;

  f32x4 acc[4][2];
#pragma unroll
  for (int fr = 0; fr < 4; ++fr)
#pragma unroll
    for (int fc = 0; fc < 2; ++fc) acc[fr][fc] = f32x4{0.f, 0.f, 0.f, 0.f};

  for (int k0 = 0; k0 < K; k0 += 32) {
#pragma unroll
    for (int rep = 0; rep < 2; ++rep) {
      int idx = tid + rep * 256;
      int row = idx >> 2, kq = (idx & 3) * 8;
      int gr = bR + row;
      bf16x8 v;
      if (gr < NNODES) {
        v = *(const bf16x8*)(A + (size_t)gr * lda + k0 + kq);
      } else {
#pragma unroll
        for (int i = 0; i < 8; ++i) v[i] = (__bf16)0.f;
      }
      *(bf16x8*)(sA + row * 40 + kq) = v;
    }
    {
      int n = tid >> 2, kq = (tid & 3) * 8;
      bf16x8 v = *(const bf16x8*)(Bt + (size_t)(bC + n) * K + k0 + kq);
      *(bf16x8*)(sB + n * 40 + kq) = v;
    }
    __syncthreads();
    bf16x8 aF[4], bF[2];
#pragma unroll
    for (int fr = 0; fr < 4; ++fr)
      aF[fr] = *(const bf16x8*)(sA + (wr * 64 + fr * 16 + lr) * 40 + lg * 8);
#pragma unroll
    for (int fc = 0; fc < 2; ++fc)
      bF[fc] = *(const bf16x8*)(sB + (wc * 32 + fc * 16 + lr) * 40 + lg * 8);
#pragma unroll
    for (int fr = 0; fr < 4; ++fr)
#pragma unroll
      for (int fc = 0; fc < 2; ++fc)
        acc[fr][fc] = __builtin_amdgcn_mfma_f32_16x16x32_bf16(
            aF[fr], bF[fc], acc[fr][fc], 0, 0, 0);
    __syncthreads();
  }

  float csum[2] = {0.f, 0.f}, csum2[2] = {0.f, 0.f};
#pragma unroll
  for (int fr = 0; fr < 4; ++fr) {
#pragma unroll
    for (int j = 0; j < 4; ++j) {
      int gr = bR + wr * 64 + fr * 16 + lg * 4 + j;
      if (gr >= NNODES) continue;
      int ct = (EPI >= 1) ? cnt[gr] : 1;
#pragma unroll
      for (int fc = 0; fc < 2; ++fc) {
        int gc = bC + wc * 32 + fc * 16 + lr;
        float v = acc[fr][fc][j];
        if (EPI == 0) {
          if (gc < dhalf) v += bias[gc];
          ((unsigned short*)Cout)[(size_t)gr * Ncol + gc] = f2bf(v);
        } else {
          v = (ct > 0) ? (v + bias[gc]) : 0.f;
          ((float*)Cout)[(size_t)gr * Ncol + gc] = v;
          if (EPI == 2) {
            csum[fc] += v;
            csum2[fc] += v * v;
          }
        }
      }
    }
  }
  if (EPI == 2) {
#pragma unroll
    for (int fc = 0; fc < 2; ++fc) {
      float s = csum[fc], s2 = csum2[fc];
      s += __shfl_xor(s, 16, 64);
      s += __shfl_xor(s, 32, 64);
      s2 += __shfl_xor(s2, 16, 64);
      s2 += __shfl_xor(s2, 32, 64);
      if (lg == 0) {
        int gc = bC + wc * 32 + fc * 16 + lr;
        atomicAdd(&stats[gc], s);
        atomicAdd(&stats[Ncol + gc], s2);
      }
    }
  }
}

// ------- edge aggregation (gather, bf16, XCD column-sliced) -------
template <int D, int SLICES>
__global__ __launch_bounds__(256) void edge_agg_kernel(
    const unsigned short* __restrict__ AV, const int* __restrict__ rowptr,
    const int* __restrict__ csr_src, unsigned short* __restrict__ Y) {
  int slice = blockIdx.x % SLICES;
  int ngrp = blockIdx.x / SLICES;
  int tid = threadIdx.x;
  int ln = tid & 7;   // 8 threads per node, 8 cols each
  int sn = tid >> 3;  // 32 nodes per block
  int node = ngrp * 32 + sn;
  if (node >= NNODES) return;
  int c = slice * 64 + ln * 8;
  const unsigned short* Arow = AV + (size_t)node * 2 * D;
  u16x8 a8 = *(const u16x8*)(Arow + c);
  u16x8 v8 = *(const u16x8*)(Arow + D + c);
  float ad[8], acc[8];
#pragma unroll
  for (int i = 0; i < 8; ++i) {
    ad[i] = bf2f(a8[i]) - bf2f(v8[i]);
    acc[i] = 0.f;
  }
  int e0 = rowptr[node], e1 = rowptr[node + 1];
  int e = e0;
  for (; e + 3 < e1; e += 4) {
    int s0 = csr_src[e], s1 = csr_src[e + 1];
    int s2 = csr_src[e + 2], s3 = csr_src[e + 3];
    u16x8 w0 = *(const u16x8*)(AV + (size_t)s0 * 2 * D + D + c);
    u16x8 w1 = *(const u16x8*)(AV + (size_t)s1 * 2 * D + D + c);
    u16x8 w2 = *(const u16x8*)(AV + (size_t)s2 * 2 * D + D + c);
    u16x8 w3 = *(const u16x8*)(AV + (size_t)s3 * 2 * D + D + c);
#pragma unroll
    for (int i = 0; i < 8; ++i) {
      acc[i] += fmaxf(ad[i] + bf2f(w0[i]), 0.f) + fmaxf(ad[i] + bf2f(w1[i]), 0.f) +
                fmaxf(ad[i] + bf2f(w2[i]), 0.f) + fmaxf(ad[i] + bf2f(w3[i]), 0.f);
    }
  }
  for (; e < e1; ++e) {
    int s0 = csr_src[e];
    u16x8 w0 = *(const u16x8*)(AV + (size_t)s0 * 2 * D + D + c);
#pragma unroll
    for (int i = 0; i < 8; ++i) acc[i] += fmaxf(ad[i] + bf2f(w0[i]), 0.f);
  }
  float inv = (e1 > e0) ? 1.f / (float)(e1 - e0) : 0.f;
  u16x8 o;
#pragma unroll
  for (int i = 0; i < 8; ++i) o[i] = f2bf(acc[i] * inv);
  *(u16x8*)(Y + (size_t)node * D + c) = o;
}

// ---------------- BN(train) + ReLU -> H (bf16) ----------------
__global__ __launch_bounds__(256) void bn_relu_kernel(
    const float* __restrict__ S, const float* __restrict__ stats,
    const float* __restrict__ g, const float* __restrict__ bb, int dout,
    unsigned short* __restrict__ Hout) {
  size_t idx = (size_t)blockIdx.x * blockDim.x + threadIdx.x;
  size_t total = (size_t)NNODES * dout;
  if (idx >= total) return;
  int c = (int)(idx % dout);
  float mu = stats[c] * (1.0f / NNODES);
  float var = stats[dout + c] * (1.0f / NNODES) - mu * mu;
  float y = S[idx];
  float v = g[c] * (y - mu) * rsqrtf(var + 1e-5f) + bb[c];
  Hout[idx] = f2bf(fmaxf(v, 0.f));
}

static void launch_edge_agg(int dout, const unsigned short* AV, const int* rowptr,
                            const int* csr_src, unsigned short* Y,
                            hipStream_t st) {
  const int NG = (NNODES + 31) / 32;  // 625 node groups
  switch (dout) {
    case 64:
      hipLaunchKernelGGL((edge_agg_kernel<64, 1>), dim3(NG * 1), dim3(256), 0, st,
                         AV, rowptr, csr_src, Y);
      break;
    case 128:
      hipLaunchKernelGGL((edge_agg_kernel<128, 2>), dim3(NG * 2), dim3(256), 0, st,
                         AV, rowptr, csr_src, Y);
      break;
    case 256:
      hipLaunchKernelGGL((edge_agg_kernel<256, 4>), dim3(NG * 4), dim3(256), 0, st,
                         AV, rowptr, csr_src, Y);
      break;
    case 512:
      hipLaunchKernelGGL((edge_agg_kernel<512, 8>), dim3(NG * 8), dim3(256), 0, st,
                         AV, rowptr, csr_src, Y);
      break;
  }
}

extern "C" void kernel_launch(void* const* d_in, const int* in_sizes, int n_in,
                              void* d_out, int out_size, void* d_ws,
                              size_t ws_size, hipStream_t stream) {
  const float* x = (const float*)d_in[0];
  const int* edge_index = (const int*)d_in[1];
  const int* esrc = edge_index;            // edge_index[0]
  const int* edst = edge_index + NEDGES;   // edge_index[1]

  const float* gw1[5] = {(const float*)d_in[3],  (const float*)d_in[7],
                         (const float*)d_in[11], (const float*)d_in[15],
                         (const float*)d_in[19]};
  const float* gb1[5] = {(const float*)d_in[4],  (const float*)d_in[8],
                         (const float*)d_in[12], (const float*)d_in[16],
                         (const float*)d_in[20]};
  const float* gw2[5] = {(const float*)d_in[5],  (const float*)d_in[9],
                         (const float*)d_in[13], (const float*)d_in[17],
                         (const float*)d_in[21]};
  const float* gb2[5] = {(const float*)d_in[6],  (const float*)d_in[10],
                         (const float*)d_in[14], (const float*)d_in[18],
                         (const float*)d_in[22]};
  const float* ng[4] = {(const float*)d_in[23], (const float*)d_in[25],
                        (const float*)d_in[27], (const float*)d_in[29]};
  const float* nb[4] = {(const float*)d_in[24], (const float*)d_in[26],
                        (const float*)d_in[28], (const float*)d_in[30]};

  // workspace layout
  unsigned short* AV = (unsigned short*)d_ws;            // N x 1024 bf16
  float* S = (float*)(AV + (size_t)NNODES * 1024);       // N x 256 f32
  unsigned short* Hbf = (unsigned short*)(S + (size_t)NNODES * 256);  // N x 256 bf16 (L1: stride 224)
  unsigned short* Ybf = Hbf + (size_t)NNODES * 256;      // N x 512 bf16
  unsigned short* Wt1All = Ybf + (size_t)NNODES * 512;   // 503808 bf16
  unsigned short* Wt2All = Wt1All + WT1_TOTAL;           // 413696 bf16
  int* cnt = (int*)(Wt2All + WT2_TOTAL);                 // N
  int* rowptr = cnt + NNODES;                            // N+1
  int* head = rowptr + NNODES + 1;                       // N
  int* csr_src = head + NNODES;                          // E
  int* bsum = csr_src + NEDGES;                          // NB
  int* boff = bsum + NB;                                 // NB
  float* stats = (float*)(boff + NB);                    // 4 layers x 1024

  const int Kpads[5] = {224, 64, 128, 256, 256};
  const int douts[5] = {64, 128, 256, 256, 512};
  const int wt1_off[5] = {0, 28672, 45056, 110592, 241664};
  const int wt2_off[5] = {0, 4096, 20480, 86016, 151552};
  const int MBLK = (NNODES + 127) / 128;  // 157

  hipMemsetAsync(cnt, 0, NNODES * sizeof(int), stream);
  hipMemsetAsync(stats, 0, 4 * 1024 * sizeof(float), stream);
  count_kernel<<<(NEDGES + 255) / 256, 256, 0, stream>>>(edst, cnt);
  scan_pass1<<<NB, 256, 0, stream>>>(cnt, bsum);
  scan_pass2<<<1, 128, 0, stream>>>(bsum, boff);
  scan_pass3<<<NB, 256, 0, stream>>>(cnt, boff, rowptr, head);
  scatter_kernel<<<(NEDGES + 255) / 256, 256, 0, stream>>>(esrc, edst, head, csr_src);
  embed_kernel<<<(NNODES + 255) / 256, 256, 0, stream>>>(x, Hbf);

  WPtrs wp;
  for (int i = 0; i < 5; ++i) { wp.w1[i] = gw1[i]; wp.w2[i] = gw2[i]; }
  weight_prep_kernel<<<(WT1_TOTAL + WT2_TOTAL + 255) / 256, 256, 0, stream>>>(
      wp, Wt1All, Wt2All);

  int lda = 224;
  for (int L = 0; L < 5; ++L) {
    int Kp = Kpads[L], dout = douts[L];
    // AV = [H@W1a + b1 | H@W1b] (bf16)
    dim3 g1(2 * dout / 64, MBLK);
    hipLaunchKernelGGL((mfma_gemm_kernel<0>), g1, dim3(256), 0, stream,
                       Hbf, lda, Kp, Wt1All + wt1_off[L], 2 * dout, dout, gb1[L],
                       (const int*)nullptr, (float*)nullptr, (void*)AV);
    // Y = scatter-mean of relu messages (gather over CSR, XCD-sliced) -> bf16
    launch_edge_agg(dout, AV, rowptr, csr_src, Ybf, stream);
    // S/out = Y @ W2 + b2 (cnt-masked), with fused column stats for layers 1-4
    dim3 g2(dout / 64, MBLK);
    if (L < 4) {
      float* lstats = stats + L * 1024;
      hipLaunchKernelGGL((mfma_gemm_kernel<2>), g2, dim3(256), 0, stream,
                         Ybf, dout, dout, Wt2All + wt2_off[L], dout, dout, gb2[L],
                         cnt, lstats, (void*)S);
      size_t total = (size_t)NNODES * dout;
      bn_relu_kernel<<<(total + 255) / 256, 256, 0, stream>>>(
          S, lstats, ng[L], nb[L], dout, Hbf);
      lda = dout;
    } else {
      hipLaunchKernelGGL((mfma_gemm_kernel<1>), g2, dim3(256), 0, stream,
                         Ybf, dout, dout, Wt2All + wt2_off[L], dout, dout, gb2[L],
                         cnt, (float*)nullptr, (void*)d_out);
    }
  }
}